// Round 1
// baseline (1658.108 us; speedup 1.0000x reference)
//
#include <hip/hip_runtime.h>
#include <math.h>

#define B_   32
#define C_   32
#define T_   1024
#define NF_  33
#define F2_  66      // NF*2
#define FD_  2112    // C_*F2_
#define NW_  961
#define MLP_ 256
#define HID_ 256
#define HH_  128
#define TN_  32
#define NT_  31      // ceil(961/32)

#define PI_F     3.14159265358979323846f
#define INV_PI_F 0.31830988618379067154f

// ---------------------------------------------------------------------------
// prep: blocks 0..32 transpose Wp (256x2112) -> WpT (2112x256); block 33 does
// softmax(agg) -> wts.
// ---------------------------------------------------------------------------
__global__ __launch_bounds__(256) void prep_kernel(const float* __restrict__ Wp,
                                                   const float* __restrict__ agg,
                                                   float* __restrict__ WpT,
                                                   float* __restrict__ wts) {
    const int blk = blockIdx.x;
    const int tid = threadIdx.x;
    __shared__ float red[256];
    if (blk < 33) {
        const int r0 = blk * 64;
        for (int rr = 0; rr < 64; ++rr) {
            const int r = r0 + rr;
            WpT[(size_t)r * MLP_ + tid] = Wp[(size_t)tid * FD_ + r];
        }
    } else {
        float mx = -INFINITY;
        for (int i = tid; i < NW_; i += 256) mx = fmaxf(mx, agg[i]);
        red[tid] = mx; __syncthreads();
        for (int s = 128; s > 0; s >>= 1) {
            if (tid < s) red[tid] = fmaxf(red[tid], red[tid + s]);
            __syncthreads();
        }
        mx = red[0]; __syncthreads();
        float sm = 0.f;
        for (int i = tid; i < NW_; i += 256) sm += expf(agg[i] - mx);
        red[tid] = sm; __syncthreads();
        for (int s = 128; s > 0; s >>= 1) {
            if (tid < s) red[tid] += red[tid + s];
            __syncthreads();
        }
        const float inv = 1.f / red[0];
        for (int i = tid; i < NW_; i += 256) wts[i] = expf(agg[i] - mx) * inv;
    }
}

// ---------------------------------------------------------------------------
// fft_proj: per block = (tile of 32 windows, one batch b).
//  - xs: x[b, :, n0 .. n0+95] staged in LDS
//  - direct DFT, thread (tf, ng): bin f=tf for 4 windows ng*4..ng*4+3,
//    window samples held in registers (overlap-shared), basisT in LDS
//    (transposed: [k][2f]=cos, [2f+1]=-sin; 2-way bank access = free)
//  - f=32 (Nyquist) special-cased on tf==0 lanes (sign-alternating sum)
//  - fused GEMM vs WpT (global, L2-resident) with 4n x 8m register tile,
//    epilogue tanh(.+bp)*pi
// ---------------------------------------------------------------------------
__global__ __launch_bounds__(256) void fft_proj_kernel(const float* __restrict__ x,
                                                       const float* __restrict__ WpT,
                                                       const float* __restrict__ bp,
                                                       float* __restrict__ proj) {
    const int tile = blockIdx.x;
    const int bb   = blockIdx.y;
    const int n0   = tile * TN_;
    const int tid  = threadIdx.x;
    const int tf   = tid & 31;   // DFT bin / GEMM m-group (m0 = tf*8)
    const int ng   = tid >> 5;   // n-group (0..7), rows ng*4..ng*4+3
    const int nl0  = ng * 4;

    __shared__ float xs[C_][96];        // 12.0 KB
    __shared__ float basisT[64][68];    // 17.4 KB
    __shared__ float featT[F2_][36];    // 9.5 KB

    // basis fill: f in [0,32), k in [0,64)
    for (int e = tid; e < 2048; e += 256) {
        const int f = e >> 6, k = e & 63;
        const int m = (f * k) & 63;
        float s, c;
        sincosf(-PI_F * (float)m / 32.0f, &s, &c);
        basisT[k][2 * f]     = c;   // cos(2*pi*f*k/64)
        basisT[k][2 * f + 1] = s;   // -sin(2*pi*f*k/64)
    }

    // xs fill (guard tail tile reading past T_)
    {
        const float* xb = x + (size_t)bb * C_ * T_;
        for (int i = tid; i < C_ * 24; i += 256) {
            const int c = i / 24, q = i - c * 24;
            const int t0 = n0 + q * 4;
            float4 v;
            if (t0 + 3 < T_) {
                v = *(const float4*)(xb + (size_t)c * T_ + t0);
            } else {
                v.x = (t0 + 0 < T_) ? xb[(size_t)c * T_ + t0 + 0] : 0.f;
                v.y = (t0 + 1 < T_) ? xb[(size_t)c * T_ + t0 + 1] : 0.f;
                v.z = (t0 + 2 < T_) ? xb[(size_t)c * T_ + t0 + 2] : 0.f;
                v.w = 0.f;
            }
            *(float4*)&xs[c][q * 4] = v;
        }
    }
    __syncthreads();

    float acc[4][8];
#pragma unroll
    for (int i = 0; i < 4; ++i)
#pragma unroll
        for (int j = 0; j < 8; ++j) acc[i][j] = 0.f;

    for (int c = 0; c < C_; ++c) {
        // ---- DFT phase (registers) ----
        float re[4] = {0.f, 0.f, 0.f, 0.f};
        float im[4] = {0.f, 0.f, 0.f, 0.f};
        float rny[4] = {0.f, 0.f, 0.f, 0.f};
#pragma unroll
        for (int half = 0; half < 2; ++half) {
            float xw[36];
#pragma unroll
            for (int q = 0; q < 9; ++q) {
                float4 v = *(const float4*)&xs[c][nl0 + half * 32 + q * 4];
                xw[q * 4 + 0] = v.x; xw[q * 4 + 1] = v.y;
                xw[q * 4 + 2] = v.z; xw[q * 4 + 3] = v.w;
            }
#pragma unroll
            for (int k = 0; k < 32; ++k) {
                const float2 w = *(const float2*)&basisT[half * 32 + k][2 * tf];
#pragma unroll
                for (int n = 0; n < 4; ++n) {
                    re[n] = fmaf(xw[n + k], w.x, re[n]);
                    im[n] = fmaf(xw[n + k], w.y, im[n]);
                }
            }
            if (tf == 0) {  // Nyquist bin: sum of (-1)^k * x
#pragma unroll
                for (int k = 0; k < 32; k += 2) {
#pragma unroll
                    for (int n = 0; n < 4; ++n) rny[n] += xw[n + k] - xw[n + k + 1];
                }
            }
        }

        __syncthreads();  // previous GEMM phase done reading featT
        {
            float4 vm, vp;
            vm.x = log1pf(sqrtf(re[0] * re[0] + im[0] * im[0]));
            vm.y = log1pf(sqrtf(re[1] * re[1] + im[1] * im[1]));
            vm.z = log1pf(sqrtf(re[2] * re[2] + im[2] * im[2]));
            vm.w = log1pf(sqrtf(re[3] * re[3] + im[3] * im[3]));
            vp.x = atan2f(im[0], re[0]) * INV_PI_F;
            vp.y = atan2f(im[1], re[1]) * INV_PI_F;
            vp.z = atan2f(im[2], re[2]) * INV_PI_F;
            vp.w = atan2f(im[3], re[3]) * INV_PI_F;
            *(float4*)&featT[2 * tf][nl0]     = vm;
            *(float4*)&featT[2 * tf + 1][nl0] = vp;
            if (tf == 0) {
                float4 a, p;
                a.x = log1pf(fabsf(rny[0])); p.x = (__float_as_uint(rny[0]) >> 31) ? 1.0f : 0.0f;
                a.y = log1pf(fabsf(rny[1])); p.y = (__float_as_uint(rny[1]) >> 31) ? 1.0f : 0.0f;
                a.z = log1pf(fabsf(rny[2])); p.z = (__float_as_uint(rny[2]) >> 31) ? 1.0f : 0.0f;
                a.w = log1pf(fabsf(rny[3])); p.w = (__float_as_uint(rny[3]) >> 31) ? 1.0f : 0.0f;
                *(float4*)&featT[64][nl0] = a;
                *(float4*)&featT[65][nl0] = p;
            }
        }
        __syncthreads();  // featT ready

        // ---- fused GEMM phase: acc[n][m] += featT[j][n] * WpT[c*66+j][m] ----
        const float* wp = WpT + ((size_t)c * F2_) * MLP_ + tf * 8;
#pragma unroll 2
        for (int j = 0; j < F2_; ++j) {
            const float4 fv = *(const float4*)&featT[j][nl0];
            const float4 w0 = *(const float4*)(wp + (size_t)j * MLP_);
            const float4 w1 = *(const float4*)(wp + (size_t)j * MLP_ + 4);
            float fvn[4] = {fv.x, fv.y, fv.z, fv.w};
#pragma unroll
            for (int n = 0; n < 4; ++n) {
                acc[n][0] = fmaf(fvn[n], w0.x, acc[n][0]);
                acc[n][1] = fmaf(fvn[n], w0.y, acc[n][1]);
                acc[n][2] = fmaf(fvn[n], w0.z, acc[n][2]);
                acc[n][3] = fmaf(fvn[n], w0.w, acc[n][3]);
                acc[n][4] = fmaf(fvn[n], w1.x, acc[n][4]);
                acc[n][5] = fmaf(fvn[n], w1.y, acc[n][5]);
                acc[n][6] = fmaf(fvn[n], w1.z, acc[n][6]);
                acc[n][7] = fmaf(fvn[n], w1.w, acc[n][7]);
            }
        }
    }

    // ---- epilogue: proj = tanh(acc + bp) * pi ----
    float bv[8];
#pragma unroll
    for (int j = 0; j < 8; ++j) bv[j] = bp[tf * 8 + j];
#pragma unroll
    for (int n = 0; n < 4; ++n) {
        const int gn = n0 + nl0 + n;
        if (gn < NW_) {
            float* pr = proj + ((size_t)bb * NW_ + gn) * MLP_ + tf * 8;
            float4 o0, o1;
            o0.x = tanhf(acc[n][0] + bv[0]) * PI_F;
            o0.y = tanhf(acc[n][1] + bv[1]) * PI_F;
            o0.z = tanhf(acc[n][2] + bv[2]) * PI_F;
            o0.w = tanhf(acc[n][3] + bv[3]) * PI_F;
            o1.x = tanhf(acc[n][4] + bv[4]) * PI_F;
            o1.y = tanhf(acc[n][5] + bv[5]) * PI_F;
            o1.z = tanhf(acc[n][6] + bv[6]) * PI_F;
            o1.w = tanhf(acc[n][7] + bv[7]) * PI_F;
            *(float4*)pr       = o0;
            *(float4*)(pr + 4) = o1;
        }
    }
}

// ---------------------------------------------------------------------------
// gemm_tanh: C[M,N] = tanh(A[M,K] @ Bm[N,K]^T + bias[N]); 128x128 tile,
// BK=16, 256 threads, 8x8 micro-tile.
// ---------------------------------------------------------------------------
__global__ __launch_bounds__(256) void gemm_tanh_kernel(const float* __restrict__ A,
                                                        const float* __restrict__ Bm,
                                                        const float* __restrict__ bias,
                                                        float* __restrict__ Cm,
                                                        int M, int N, int Kd) {
    const int bm = blockIdx.x, bn = blockIdx.y;
    const int tid = threadIdx.x;
    const int tx = tid & 15, ty = tid >> 4;
    const int row0 = bm * 128, col0 = bn * 128;

    __shared__ float As[16][132];
    __shared__ float Bs[16][132];

    float acc[8][8];
#pragma unroll
    for (int i = 0; i < 8; ++i)
#pragma unroll
        for (int j = 0; j < 8; ++j) acc[i][j] = 0.f;

    for (int k0 = 0; k0 < Kd; k0 += 16) {
#pragma unroll
        for (int rep = 0; rep < 2; ++rep) {
            const int i = tid + rep * 256;     // 0..511
            const int r = i >> 2;
            const int kq4 = (i & 3) * 4;
            const int gr = row0 + r;
            float4 v = {0.f, 0.f, 0.f, 0.f};
            if (gr < M) v = *(const float4*)(A + (size_t)gr * Kd + k0 + kq4);
            As[kq4 + 0][r] = v.x; As[kq4 + 1][r] = v.y;
            As[kq4 + 2][r] = v.z; As[kq4 + 3][r] = v.w;
            const int gc = col0 + r;
            float4 w = {0.f, 0.f, 0.f, 0.f};
            if (gc < N) w = *(const float4*)(Bm + (size_t)gc * Kd + k0 + kq4);
            Bs[kq4 + 0][r] = w.x; Bs[kq4 + 1][r] = w.y;
            Bs[kq4 + 2][r] = w.z; Bs[kq4 + 3][r] = w.w;
        }
        __syncthreads();
#pragma unroll
        for (int kk = 0; kk < 16; ++kk) {
            float a[8], b[8];
            *(float4*)&a[0] = *(const float4*)&As[kk][ty * 8];
            *(float4*)&a[4] = *(const float4*)&As[kk][ty * 8 + 4];
            *(float4*)&b[0] = *(const float4*)&Bs[kk][tx * 8];
            *(float4*)&b[4] = *(const float4*)&Bs[kk][tx * 8 + 4];
#pragma unroll
            for (int i = 0; i < 8; ++i)
#pragma unroll
                for (int j = 0; j < 8; ++j) acc[i][j] = fmaf(a[i], b[j], acc[i][j]);
        }
        __syncthreads();
    }

    float bv[8];
#pragma unroll
    for (int j = 0; j < 8; ++j) bv[j] = bias[col0 + tx * 8 + j];
#pragma unroll
    for (int i = 0; i < 8; ++i) {
        const int gr = row0 + ty * 8 + i;
        if (gr < M) {
            float* cp = Cm + (size_t)gr * N + col0 + tx * 8;
            float4 o0, o1;
            o0.x = tanhf(acc[i][0] + bv[0]);
            o0.y = tanhf(acc[i][1] + bv[1]);
            o0.z = tanhf(acc[i][2] + bv[2]);
            o0.w = tanhf(acc[i][3] + bv[3]);
            o1.x = tanhf(acc[i][4] + bv[4]);
            o1.y = tanhf(acc[i][5] + bv[5]);
            o1.z = tanhf(acc[i][6] + bv[6]);
            o1.w = tanhf(acc[i][7] + bv[7]);
            *(float4*)cp       = o0;
            *(float4*)(cp + 4) = o1;
        }
    }
}

// ---------------------------------------------------------------------------
// out_reduce: per b, out[b] = sum_n (h2[b,n,:]·Wout + bout) * wts[n]
// ---------------------------------------------------------------------------
__global__ __launch_bounds__(256) void out_reduce_kernel(const float* __restrict__ h2,
                                                         const float* __restrict__ Wout,
                                                         const float* __restrict__ bout,
                                                         const float* __restrict__ wts,
                                                         float* __restrict__ out) {
    const int bb = blockIdx.x;
    const int tid = threadIdx.x;
    __shared__ float wsh[HH_];
    __shared__ float red[256];
    if (tid < HH_) wsh[tid] = Wout[tid];
    __syncthreads();
    const float bo = bout[0];
    float acc = 0.f;
    for (int n = tid; n < NW_; n += 256) {
        const float* row = h2 + ((size_t)bb * NW_ + n) * HH_;
        float dot = 0.f;
#pragma unroll
        for (int j = 0; j < HH_; j += 4) {
            const float4 v = *(const float4*)(row + j);
            dot += v.x * wsh[j] + v.y * wsh[j + 1] + v.z * wsh[j + 2] + v.w * wsh[j + 3];
        }
        acc += (dot + bo) * wts[n];
    }
    red[tid] = acc;
    __syncthreads();
    for (int s = 128; s > 0; s >>= 1) {
        if (tid < s) red[tid] += red[tid + s];
        __syncthreads();
    }
    if (tid == 0) out[bb] = red[0];
}

// ---------------------------------------------------------------------------
extern "C" void kernel_launch(void* const* d_in, const int* in_sizes, int n_in,
                              void* d_out, int out_size, void* d_ws, size_t ws_size,
                              hipStream_t stream) {
    const float* x    = (const float*)d_in[0];
    const float* Wp   = (const float*)d_in[1];
    const float* bp   = (const float*)d_in[2];
    const float* W1   = (const float*)d_in[3];
    const float* b1   = (const float*)d_in[4];
    const float* W2   = (const float*)d_in[5];
    const float* b2   = (const float*)d_in[6];
    const float* Wout = (const float*)d_in[7];
    const float* bout = (const float*)d_in[8];
    const float* agg  = (const float*)d_in[9];
    float* out = (float*)d_out;
    float* ws  = (float*)d_ws;

    const size_t wpT_off  = 0;                // 2112*256 = 540672 floats
    const size_t wts_off  = 540672;           // 961 floats
    const size_t base_off = 541696;           // aligned
    const size_t avail    = ws_size / 4;      // floats
    const size_t per_b    = (size_t)NW_ * (MLP_ + HID_ + HH_);  // 615040 floats

    int NB = 32;
    if (base_off + (size_t)32 * per_b > avail) {
        size_t nbmax = (avail > base_off) ? (avail - base_off) / per_b : 1;
        if (nbmax < 1) nbmax = 1;
        if (nbmax > 32) nbmax = 32;
        NB = (int)nbmax;
    }

    float* WpT  = ws + wpT_off;
    float* wts  = ws + wts_off;
    float* proj = ws + base_off;
    float* h1   = proj + (size_t)NB * NW_ * MLP_;
    float* h2   = h1 + (size_t)NB * NW_ * HID_;

    prep_kernel<<<dim3(34), dim3(256), 0, stream>>>(Wp, agg, WpT, wts);

    for (int b0 = 0; b0 < B_; b0 += NB) {
        const int nb = (B_ - b0 < NB) ? (B_ - b0) : NB;
        fft_proj_kernel<<<dim3(NT_, nb), dim3(256), 0, stream>>>(
            x + (size_t)b0 * C_ * T_, WpT, bp, proj);
        const int M = nb * NW_;
        gemm_tanh_kernel<<<dim3((M + 127) / 128, MLP_ / 128), dim3(256), 0, stream>>>(
            proj, W1, b1, h1, M, HID_, MLP_);
        gemm_tanh_kernel<<<dim3((M + 127) / 128, HH_ / 128), dim3(256), 0, stream>>>(
            h1, W2, b2, h2, M, HH_, HID_);
        out_reduce_kernel<<<dim3(nb), dim3(256), 0, stream>>>(
            h2, Wout, bout, wts, out + b0);
    }
}

// Round 2
// 1019.441 us; speedup vs baseline: 1.6265x; 1.6265x over previous
//
#include <hip/hip_runtime.h>
#include <math.h>

#define B_   32
#define C_   32
#define T_   1024
#define NF_  33
#define F2_  66      // NF*2
#define FD_  2112    // C_*F2_
#define NW_  961
#define MLP_ 256
#define HID_ 256
#define HH_  128
#define TN_  32
#define NT_  31      // ceil(961/32)

#define PI_F     3.14159265358979323846f
#define INV_PI_F 0.31830988618379067154f

typedef unsigned short u16;
typedef __attribute__((ext_vector_type(8))) short bf16x8;
typedef __attribute__((ext_vector_type(4))) float f32x4;

__device__ __forceinline__ u16 f2bf(float f) {
    unsigned u = __float_as_uint(f);
    u = u + 0x7FFFu + ((u >> 16) & 1u);   // RNE
    return (u16)(u >> 16);
}
__device__ __forceinline__ float bf2f(u16 h) {
    return __uint_as_float((unsigned)h << 16);
}
__device__ __forceinline__ void gload16(const void* g, void* l) {
    __builtin_amdgcn_global_load_lds(
        (const __attribute__((address_space(1))) void*)g,
        (__attribute__((address_space(3))) void*)l, 16, 0, 0);
}

// ---------------------------------------------------------------------------
// wconv: Wp (fp32 [256][2112]) -> bf16 hi/lo pair (same layout = B^T for MFMA)
// ---------------------------------------------------------------------------
__global__ __launch_bounds__(256) void wconv_kernel(const float* __restrict__ Wp,
                                                    u16* __restrict__ WpH,
                                                    u16* __restrict__ WpL,
                                                    int total) {
    for (int i = blockIdx.x * 256 + threadIdx.x; i < total; i += gridDim.x * 256) {
        const float v = Wp[i];
        const u16 h = f2bf(v);
        WpH[i] = h;
        WpL[i] = f2bf(v - bf2f(h));
    }
}

// ---------------------------------------------------------------------------
// softmax(agg) -> wts (single block)
// ---------------------------------------------------------------------------
__global__ __launch_bounds__(256) void softmax_kernel(const float* __restrict__ agg,
                                                      float* __restrict__ wts) {
    const int tid = threadIdx.x;
    __shared__ float red[256];
    float mx = -INFINITY;
    for (int i = tid; i < NW_; i += 256) mx = fmaxf(mx, agg[i]);
    red[tid] = mx; __syncthreads();
    for (int s = 128; s > 0; s >>= 1) {
        if (tid < s) red[tid] = fmaxf(red[tid], red[tid + s]);
        __syncthreads();
    }
    mx = red[0]; __syncthreads();
    float sm = 0.f;
    for (int i = tid; i < NW_; i += 256) sm += expf(agg[i] - mx);
    red[tid] = sm; __syncthreads();
    for (int s = 128; s > 0; s >>= 1) {
        if (tid < s) red[tid] += red[tid + s];
        __syncthreads();
    }
    const float inv = 1.f / red[0];
    for (int i = tid; i < NW_; i += 256) wts[i] = expf(agg[i] - mx) * inv;
}

// ---------------------------------------------------------------------------
// feat: per block = (tile of 32 windows, batch bb within chunk). Direct DFT
// (basis in LDS, window samples in registers), mag/phase, write bf16 hi/lo to
// feat[M][2112]. No syncthreads inside the channel loop.
// ---------------------------------------------------------------------------
__global__ __launch_bounds__(256) void feat_kernel(const float* __restrict__ x,
                                                   u16* __restrict__ featH,
                                                   u16* __restrict__ featL) {
    const int tile = blockIdx.x;
    const int bb   = blockIdx.y;
    const int n0   = tile * TN_;
    const int tid  = threadIdx.x;
    const int tf   = tid & 31;   // DFT bin
    const int ng   = tid >> 5;   // window group (4 windows)
    const int nl0  = ng * 4;

    __shared__ float xs[C_][96];        // 12.0 KB
    __shared__ float basisT[64][F2_];   // 16.9 KB

    for (int e = tid; e < 2048; e += 256) {
        const int f = e >> 6, k = e & 63;
        const int m = (f * k) & 63;
        float s, c;
        sincosf(-PI_F * (float)m / 32.0f, &s, &c);
        basisT[k][2 * f]     = c;   // cos
        basisT[k][2 * f + 1] = s;   // -sin
    }
    {
        const float* xb = x + (size_t)bb * C_ * T_;
        for (int i = tid; i < C_ * 24; i += 256) {
            const int c = i / 24, q = i - c * 24;
            const int t0 = n0 + q * 4;
            float4 v;
            if (t0 + 3 < T_) {
                v = *(const float4*)(xb + (size_t)c * T_ + t0);
            } else {
                v.x = (t0 + 0 < T_) ? xb[(size_t)c * T_ + t0 + 0] : 0.f;
                v.y = (t0 + 1 < T_) ? xb[(size_t)c * T_ + t0 + 1] : 0.f;
                v.z = (t0 + 2 < T_) ? xb[(size_t)c * T_ + t0 + 2] : 0.f;
                v.w = 0.f;
            }
            *(float4*)&xs[c][q * 4] = v;
        }
    }
    __syncthreads();

    const int mrow_base = bb * NW_;
    for (int c = 0; c < C_; ++c) {
        float re[4] = {0.f, 0.f, 0.f, 0.f};
        float im[4] = {0.f, 0.f, 0.f, 0.f};
        float rny[4] = {0.f, 0.f, 0.f, 0.f};
#pragma unroll
        for (int half = 0; half < 2; ++half) {
            float xw[36];
#pragma unroll
            for (int q = 0; q < 9; ++q) {
                float4 v = *(const float4*)&xs[c][nl0 + half * 32 + q * 4];
                xw[q * 4 + 0] = v.x; xw[q * 4 + 1] = v.y;
                xw[q * 4 + 2] = v.z; xw[q * 4 + 3] = v.w;
            }
#pragma unroll
            for (int k = 0; k < 32; ++k) {
                const float2 wv = *(const float2*)&basisT[half * 32 + k][2 * tf];
#pragma unroll
                for (int n = 0; n < 4; ++n) {
                    re[n] = fmaf(xw[n + k], wv.x, re[n]);
                    im[n] = fmaf(xw[n + k], wv.y, im[n]);
                }
            }
            if (tf == 0) {
#pragma unroll
                for (int k = 0; k < 32; k += 2) {
#pragma unroll
                    for (int n = 0; n < 4; ++n) rny[n] += xw[n + k] - xw[n + k + 1];
                }
            }
        }
#pragma unroll
        for (int n = 0; n < 4; ++n) {
            const int gn = n0 + nl0 + n;
            if (gn >= NW_) continue;
            const size_t base = (size_t)(mrow_base + gn) * FD_ + (size_t)c * F2_;
            const float mag = log1pf(sqrtf(re[n] * re[n] + im[n] * im[n]));
            const float ph  = atan2f(im[n], re[n]) * INV_PI_F;
            u16 h = f2bf(mag);
            featH[base + 2 * tf] = h;
            featL[base + 2 * tf] = f2bf(mag - bf2f(h));
            h = f2bf(ph);
            featH[base + 2 * tf + 1] = h;
            featL[base + 2 * tf + 1] = f2bf(ph - bf2f(h));
            if (tf == 0) {  // Nyquist bin -> columns 64 (mag), 65 (phase)
                const float a = log1pf(fabsf(rny[n]));
                const float p = (__float_as_uint(rny[n]) >> 31) ? 1.0f : 0.0f;
                h = f2bf(a);
                featH[base + 64] = h; featL[base + 64] = f2bf(a - bf2f(h));
                h = f2bf(p);
                featH[base + 65] = h; featL[base + 65] = f2bf(p - bf2f(h));
            }
        }
    }
}

// ---------------------------------------------------------------------------
// proj_mfma: proj[M][256] = tanh(feat @ Wp^T + bp) * pi via 3-term bf16 split
// (Ah*Bh + Ah*Bl + Al*Bh), fp32 accum. 128x128 tile, BK=32, 4 waves, each
// wave 64x64 (4x4 frags of 16x16x32). global_load_lds width-16 staging.
// A = feat[M][2112] row-major; B^T = Wp[256][2112] row-major (same strides).
// ---------------------------------------------------------------------------
__global__ __launch_bounds__(256) void proj_mfma_kernel(
        const u16* __restrict__ featH, const u16* __restrict__ featL,
        const u16* __restrict__ WpH,  const u16* __restrict__ WpL,
        const float* __restrict__ bp, float* __restrict__ proj, int Mvalid) {
    const int bm = blockIdx.x, bn = blockIdx.y;
    const int tid = threadIdx.x;
    const int lane = tid & 63, w = tid >> 6;
    const int wr = w >> 1, wc = w & 1;
    const int m0 = bm * 128, n0 = bn * 128;

    __shared__ u16 AsH[128 * 32];   // 8 KB each, 32 KB total
    __shared__ u16 AsL[128 * 32];
    __shared__ u16 BsH[128 * 32];
    __shared__ u16 BsL[128 * 32];

    f32x4 acc[4][4];
#pragma unroll
    for (int i = 0; i < 4; ++i)
#pragma unroll
        for (int j = 0; j < 4; ++j) acc[i][j] = (f32x4){0.f, 0.f, 0.f, 0.f};

    const char* gAh = (const char*)featH + (size_t)m0 * (FD_ * 2);
    const char* gAl = (const char*)featL + (size_t)m0 * (FD_ * 2);
    const char* gBh = (const char*)WpH  + (size_t)n0 * (FD_ * 2);
    const char* gBl = (const char*)WpL  + (size_t)n0 * (FD_ * 2);

    const int r0   = tid >> 2;          // tile row covered by this lane
    const int kb0  = (tid & 3) * 16;    // byte offset within 64B row
    const int loff0 = tid * 16;         // linear LDS byte offset (lane-ordered)

    const int abase = (wr * 64 + (lane & 15)) * 64 + (lane >> 4) * 16;
    const int bbase = (wc * 64 + (lane & 15)) * 64 + (lane >> 4) * 16;

    for (int k0 = 0; k0 < FD_; k0 += 32) {
#pragma unroll
        for (int i = 0; i < 2; ++i) {
            const size_t goff = (size_t)(r0 + i * 64) * (FD_ * 2) + (size_t)(k0 * 2 + kb0);
            const int loff = loff0 + i * 4096;
            gload16(gAh + goff, (char*)AsH + loff);
            gload16(gAl + goff, (char*)AsL + loff);
            gload16(gBh + goff, (char*)BsH + loff);
            gload16(gBl + goff, (char*)BsL + loff);
        }
        __syncthreads();   // compiler drains vmcnt before s_barrier

        bf16x8 ah[4], al[4], bh[4], bl[4];
#pragma unroll
        for (int f = 0; f < 4; ++f) {
            ah[f] = *(const bf16x8*)((const char*)AsH + abase + f * 1024);
            al[f] = *(const bf16x8*)((const char*)AsL + abase + f * 1024);
            bh[f] = *(const bf16x8*)((const char*)BsH + bbase + f * 1024);
            bl[f] = *(const bf16x8*)((const char*)BsL + bbase + f * 1024);
        }
#pragma unroll
        for (int fm = 0; fm < 4; ++fm)
#pragma unroll
            for (int fn = 0; fn < 4; ++fn) {
                acc[fm][fn] = __builtin_amdgcn_mfma_f32_16x16x32_bf16(ah[fm], bh[fn], acc[fm][fn], 0, 0, 0);
                acc[fm][fn] = __builtin_amdgcn_mfma_f32_16x16x32_bf16(ah[fm], bl[fn], acc[fm][fn], 0, 0, 0);
                acc[fm][fn] = __builtin_amdgcn_mfma_f32_16x16x32_bf16(al[fm], bh[fn], acc[fm][fn], 0, 0, 0);
            }
        __syncthreads();
    }

    float bv[4];
#pragma unroll
    for (int fn = 0; fn < 4; ++fn) bv[fn] = bp[n0 + wc * 64 + fn * 16 + (lane & 15)];
#pragma unroll
    for (int fm = 0; fm < 4; ++fm) {
        const int rbase = m0 + wr * 64 + fm * 16 + (lane >> 4) * 4;
#pragma unroll
        for (int fn = 0; fn < 4; ++fn) {
            const int col = n0 + wc * 64 + fn * 16 + (lane & 15);
#pragma unroll
            for (int r = 0; r < 4; ++r) {
                const int row = rbase + r;
                if (row < Mvalid)
                    proj[(size_t)row * MLP_ + col] = tanhf(acc[fm][fn][r] + bv[fn]) * PI_F;
            }
        }
    }
}

// ---------------------------------------------------------------------------
// gemm_tanh: C[M,N] = tanh(A[M,K] @ Bm[N,K]^T + bias[N]); fp32, 128x128 tile.
// ---------------------------------------------------------------------------
__global__ __launch_bounds__(256) void gemm_tanh_kernel(const float* __restrict__ A,
                                                        const float* __restrict__ Bm,
                                                        const float* __restrict__ bias,
                                                        float* __restrict__ Cm,
                                                        int M, int N, int Kd) {
    const int bm = blockIdx.x, bn = blockIdx.y;
    const int tid = threadIdx.x;
    const int tx = tid & 15, ty = tid >> 4;
    const int row0 = bm * 128, col0 = bn * 128;

    __shared__ float As[16][132];
    __shared__ float Bs[16][132];

    float acc[8][8];
#pragma unroll
    for (int i = 0; i < 8; ++i)
#pragma unroll
        for (int j = 0; j < 8; ++j) acc[i][j] = 0.f;

    for (int k0 = 0; k0 < Kd; k0 += 16) {
#pragma unroll
        for (int rep = 0; rep < 2; ++rep) {
            const int i = tid + rep * 256;
            const int r = i >> 2;
            const int kq4 = (i & 3) * 4;
            const int gr = row0 + r;
            float4 v = {0.f, 0.f, 0.f, 0.f};
            if (gr < M) v = *(const float4*)(A + (size_t)gr * Kd + k0 + kq4);
            As[kq4 + 0][r] = v.x; As[kq4 + 1][r] = v.y;
            As[kq4 + 2][r] = v.z; As[kq4 + 3][r] = v.w;
            const int gc = col0 + r;
            float4 wv = {0.f, 0.f, 0.f, 0.f};
            if (gc < N) wv = *(const float4*)(Bm + (size_t)gc * Kd + k0 + kq4);
            Bs[kq4 + 0][r] = wv.x; Bs[kq4 + 1][r] = wv.y;
            Bs[kq4 + 2][r] = wv.z; Bs[kq4 + 3][r] = wv.w;
        }
        __syncthreads();
#pragma unroll
        for (int kk = 0; kk < 16; ++kk) {
            float a[8], b[8];
            *(float4*)&a[0] = *(const float4*)&As[kk][ty * 8];
            *(float4*)&a[4] = *(const float4*)&As[kk][ty * 8 + 4];
            *(float4*)&b[0] = *(const float4*)&Bs[kk][tx * 8];
            *(float4*)&b[4] = *(const float4*)&Bs[kk][tx * 8 + 4];
#pragma unroll
            for (int i = 0; i < 8; ++i)
#pragma unroll
                for (int j = 0; j < 8; ++j) acc[i][j] = fmaf(a[i], b[j], acc[i][j]);
        }
        __syncthreads();
    }

    float bv[8];
#pragma unroll
    for (int j = 0; j < 8; ++j) bv[j] = bias[col0 + tx * 8 + j];
#pragma unroll
    for (int i = 0; i < 8; ++i) {
        const int gr = row0 + ty * 8 + i;
        if (gr < M) {
            float* cp = Cm + (size_t)gr * N + col0 + tx * 8;
            float4 o0, o1;
            o0.x = tanhf(acc[i][0] + bv[0]);
            o0.y = tanhf(acc[i][1] + bv[1]);
            o0.z = tanhf(acc[i][2] + bv[2]);
            o0.w = tanhf(acc[i][3] + bv[3]);
            o1.x = tanhf(acc[i][4] + bv[4]);
            o1.y = tanhf(acc[i][5] + bv[5]);
            o1.z = tanhf(acc[i][6] + bv[6]);
            o1.w = tanhf(acc[i][7] + bv[7]);
            *(float4*)cp       = o0;
            *(float4*)(cp + 4) = o1;
        }
    }
}

// ---------------------------------------------------------------------------
// out_reduce: per b, out[b] = sum_n (h2[b,n,:]·Wout + bout) * wts[n]
// ---------------------------------------------------------------------------
__global__ __launch_bounds__(256) void out_reduce_kernel(const float* __restrict__ h2,
                                                         const float* __restrict__ Wout,
                                                         const float* __restrict__ bout,
                                                         const float* __restrict__ wts,
                                                         float* __restrict__ out) {
    const int bb = blockIdx.x;
    const int tid = threadIdx.x;
    __shared__ float wsh[HH_];
    __shared__ float red[256];
    if (tid < HH_) wsh[tid] = Wout[tid];
    __syncthreads();
    const float bo = bout[0];
    float acc = 0.f;
    for (int n = tid; n < NW_; n += 256) {
        const float* row = h2 + ((size_t)bb * NW_ + n) * HH_;
        float dot = 0.f;
#pragma unroll
        for (int j = 0; j < HH_; j += 4) {
            const float4 v = *(const float4*)(row + j);
            dot += v.x * wsh[j] + v.y * wsh[j + 1] + v.z * wsh[j + 2] + v.w * wsh[j + 3];
        }
        acc += (dot + bo) * wts[n];
    }
    red[tid] = acc;
    __syncthreads();
    for (int s = 128; s > 0; s >>= 1) {
        if (tid < s) red[tid] += red[tid + s];
        __syncthreads();
    }
    if (tid == 0) out[bb] = red[0];
}

// ---------------------------------------------------------------------------
extern "C" void kernel_launch(void* const* d_in, const int* in_sizes, int n_in,
                              void* d_out, int out_size, void* d_ws, size_t ws_size,
                              hipStream_t stream) {
    const float* x    = (const float*)d_in[0];
    const float* Wp   = (const float*)d_in[1];
    const float* bp   = (const float*)d_in[2];
    const float* W1   = (const float*)d_in[3];
    const float* b1   = (const float*)d_in[4];
    const float* W2   = (const float*)d_in[5];
    const float* b2   = (const float*)d_in[6];
    const float* Wout = (const float*)d_in[7];
    const float* bout = (const float*)d_in[8];
    const float* agg  = (const float*)d_in[9];
    float* out = (float*)d_out;

    char* wsb = (char*)d_ws;
    size_t off = 0;
    auto alloc = [&](size_t bytes) -> char* {
        char* p = wsb + off;
        off += (bytes + 255) & ~(size_t)255;
        return p;
    };

    u16* WpH = (u16*)alloc((size_t)MLP_ * FD_ * 2);
    u16* WpL = (u16*)alloc((size_t)MLP_ * FD_ * 2);
    float* wts = (float*)alloc((size_t)NW_ * 4);

    const size_t fixed = off;
    int NB = 32;
    size_t Mpad = 0;
    for (;;) {
        const size_t M = (size_t)NB * NW_;
        Mpad = ((M + 127) / 128) * 128;
        const size_t need =
            2 * ((Mpad * FD_ * 2 + 255) & ~(size_t)255) +
            ((M * MLP_ * 4 + 255) & ~(size_t)255) +
            ((M * HID_ * 4 + 255) & ~(size_t)255) +
            ((M * HH_ * 4 + 255) & ~(size_t)255);
        if (fixed + need <= ws_size || NB == 1) break;
        NB >>= 1;
    }
    u16* featH = (u16*)alloc(Mpad * FD_ * 2);
    u16* featL = (u16*)alloc(Mpad * FD_ * 2);
    float* proj = (float*)alloc((size_t)NB * NW_ * MLP_ * 4);
    float* h1   = (float*)alloc((size_t)NB * NW_ * HID_ * 4);
    float* h2   = (float*)alloc((size_t)NB * NW_ * HH_ * 4);

    wconv_kernel<<<dim3(256), dim3(256), 0, stream>>>(Wp, WpH, WpL, MLP_ * FD_);
    softmax_kernel<<<dim3(1), dim3(256), 0, stream>>>(agg, wts);

    for (int b0 = 0; b0 < B_; b0 += NB) {
        const int nb = (B_ - b0 < NB) ? (B_ - b0) : NB;
        const int M = nb * NW_;
        const int MpadC = ((M + 127) / 128) * 128;
        feat_kernel<<<dim3(NT_, nb), dim3(256), 0, stream>>>(
            x + (size_t)b0 * C_ * T_, featH, featL);
        proj_mfma_kernel<<<dim3(MpadC / 128, 2), dim3(256), 0, stream>>>(
            featH, featL, WpH, WpL, bp, proj, M);
        gemm_tanh_kernel<<<dim3((M + 127) / 128, HID_ / 128), dim3(256), 0, stream>>>(
            proj, W1, b1, h1, M, HID_, MLP_);
        gemm_tanh_kernel<<<dim3((M + 127) / 128, HH_ / 128), dim3(256), 0, stream>>>(
            h1, W2, b2, h2, M, HH_, HID_);
        out_reduce_kernel<<<dim3(nb), dim3(256), 0, stream>>>(
            h2, Wout, bout, wts, out + b0);
    }
}

// Round 3
// 487.857 us; speedup vs baseline: 3.3988x; 2.0896x over previous
//
#include <hip/hip_runtime.h>
#include <math.h>

#define B_   32
#define C_   32
#define T_   1024
#define NF_  33
#define F2_  66      // NF*2
#define FD_  2112    // C_*F2_
#define NW_  961
#define MLP_ 256
#define HID_ 256
#define HH_  128
#define TN_  32
#define NT_  31      // ceil(961/32)

#define PI_F     3.14159265358979323846f
#define LN2_F    0.69314718055994530942f
#define L2E2_F   2.88539008177792681472f   // 2*log2(e)

typedef unsigned short u16;
typedef unsigned int   u32;
typedef __attribute__((ext_vector_type(8))) short bf16x8;
typedef __attribute__((ext_vector_type(4))) float f32x4;

__device__ __forceinline__ u16 f2bf(float f) {
    u32 u = __float_as_uint(f);
    u = u + 0x7FFFu + ((u >> 16) & 1u);   // RNE
    return (u16)(u >> 16);
}
__device__ __forceinline__ float bf2f(u16 h) {
    return __uint_as_float((u32)h << 16);
}
__device__ __forceinline__ void gload16(const void* g, void* l) {
    __builtin_amdgcn_global_load_lds(
        (const __attribute__((address_space(1))) void*)g,
        (__attribute__((address_space(3))) void*)l, 16, 0, 0);
}
__device__ __forceinline__ float ftanh(float x) {
    // tanh(x) = 1 - 2/(exp(2x)+1); exp2-based, inf-safe at both ends
    float z = __builtin_amdgcn_exp2f(x * L2E2_F);
    return 1.f - 2.f * __builtin_amdgcn_rcpf(z + 1.f);
}
__device__ __forceinline__ float flog1p(float x) {
    return __builtin_amdgcn_logf(1.f + x) * LN2_F;   // v_log_f32 is log2
}
// atan2(y,x)/pi, poly max err ~2e-6 (in pi units)
__device__ __forceinline__ float fatan2pi(float y, float x) {
    const float ay = fabsf(y), ax = fabsf(x);
    const float mn = fminf(ay, ax), mx = fmaxf(ay, ax);
    float t = mn * __builtin_amdgcn_rcpf(mx);
    t = (mx == 0.f) ? 0.f : t;
    const float s = t * t;
    float p = -0.00373098f;
    p = fmaf(p, s,  0.01676008f);
    p = fmaf(p, s, -0.03706162f);
    p = fmaf(p, s,  0.06160679f);
    p = fmaf(p, s, -0.10587735f);
    p = fmaf(p, s,  0.31830265f);
    p *= t;
    p = (ay > ax) ? 0.5f - p : p;
    p = (x < 0.f) ? 1.0f - p : p;
    return copysignf(p, y);
}

// ---------------------------------------------------------------------------
// wconv: fp32 weight matrix -> bf16 hi/lo planes (same layout)
// ---------------------------------------------------------------------------
__global__ __launch_bounds__(256) void wconv_kernel(const float* __restrict__ W,
                                                    u16* __restrict__ WH,
                                                    u16* __restrict__ WL,
                                                    int total) {
    for (int i = blockIdx.x * 256 + threadIdx.x; i < total; i += gridDim.x * 256) {
        const float v = W[i];
        const u16 h = f2bf(v);
        WH[i] = h;
        WL[i] = f2bf(v - bf2f(h));
    }
}

// ---------------------------------------------------------------------------
// softmax(agg) -> wts (single block)
// ---------------------------------------------------------------------------
__global__ __launch_bounds__(256) void softmax_kernel(const float* __restrict__ agg,
                                                      float* __restrict__ wts) {
    const int tid = threadIdx.x;
    __shared__ float red[256];
    float mx = -INFINITY;
    for (int i = tid; i < NW_; i += 256) mx = fmaxf(mx, agg[i]);
    red[tid] = mx; __syncthreads();
    for (int s = 128; s > 0; s >>= 1) {
        if (tid < s) red[tid] = fmaxf(red[tid], red[tid + s]);
        __syncthreads();
    }
    mx = red[0]; __syncthreads();
    float sm = 0.f;
    for (int i = tid; i < NW_; i += 256) sm += expf(agg[i] - mx);
    red[tid] = sm; __syncthreads();
    for (int s = 128; s > 0; s >>= 1) {
        if (tid < s) red[tid] += red[tid + s];
        __syncthreads();
    }
    const float inv = 1.f / red[0];
    for (int i = tid; i < NW_; i += 256) wts[i] = expf(agg[i] - mx) * inv;
}

// ---------------------------------------------------------------------------
// feat v2: grid (31 tiles, 4 channel-groups, nb). 8-channel loop per block.
// DFT bin per lane (tf), 4 windows (ng). Packs (mag,ph) bf16 into one u32
// store per (channel, window). No featL plane.
// ---------------------------------------------------------------------------
__global__ __launch_bounds__(256) void feat_kernel(const float* __restrict__ x,
                                                   u32* __restrict__ featP) {
    const int n0 = blockIdx.x * TN_;
    const int cg = blockIdx.y;
    const int bb = blockIdx.z;
    const int tid = threadIdx.x;
    const int tf = tid & 31, ng = tid >> 5, nl0 = ng * 4;

    __shared__ float2 stab[64];
    __shared__ float xs[8][96];          // 3.0 KB
    __shared__ float basisT[64][66];     // 16.9 KB

    if (tid < 64) {
        float s, c;
        sincosf(-PI_F * (float)tid / 32.0f, &s, &c);
        stab[tid] = make_float2(c, s);   // (cos, -sin) of pi*m/32
    }
    __syncthreads();
    for (int e = tid; e < 2048; e += 256) {
        const int f = e >> 6, k = e & 63;
        const float2 w = stab[(f * k) & 63];
        basisT[k][2 * f]     = w.x;
        basisT[k][2 * f + 1] = w.y;
    }
    if (tid < 192) {
        const int c8 = tid / 24, q = tid % 24;
        const int c = cg * 8 + c8;
        const int t0 = n0 + q * 4;
        const float* xb = x + ((size_t)bb * C_ + c) * T_;
        float4 v;
        if (t0 + 3 < T_) {
            v = *(const float4*)(xb + t0);
        } else {
            v.x = (t0 + 0 < T_) ? xb[t0 + 0] : 0.f;
            v.y = (t0 + 1 < T_) ? xb[t0 + 1] : 0.f;
            v.z = (t0 + 2 < T_) ? xb[t0 + 2] : 0.f;
            v.w = 0.f;
        }
        *(float4*)&xs[c8][q * 4] = v;
    }
    __syncthreads();

    const int mrow_base = bb * NW_;
    for (int c8 = 0; c8 < 8; ++c8) {
        const int c = cg * 8 + c8;
        float re[4] = {0.f, 0.f, 0.f, 0.f};
        float im[4] = {0.f, 0.f, 0.f, 0.f};
        float rny[4] = {0.f, 0.f, 0.f, 0.f};
#pragma unroll
        for (int half = 0; half < 2; ++half) {
            float xw[36];
#pragma unroll
            for (int q = 0; q < 9; ++q) {
                float4 v = *(const float4*)&xs[c8][nl0 + half * 32 + q * 4];
                xw[q * 4 + 0] = v.x; xw[q * 4 + 1] = v.y;
                xw[q * 4 + 2] = v.z; xw[q * 4 + 3] = v.w;
            }
#pragma unroll
            for (int k = 0; k < 32; ++k) {
                const float2 wv = *(const float2*)&basisT[half * 32 + k][2 * tf];
#pragma unroll
                for (int n = 0; n < 4; ++n) {
                    re[n] = fmaf(xw[n + k], wv.x, re[n]);
                    im[n] = fmaf(xw[n + k], wv.y, im[n]);
                }
            }
            if (tf == 0) {
#pragma unroll
                for (int k = 0; k < 32; k += 2) {
#pragma unroll
                    for (int n = 0; n < 4; ++n) rny[n] += xw[n + k] - xw[n + k + 1];
                }
            }
        }
#pragma unroll
        for (int n = 0; n < 4; ++n) {
            const int gn = n0 + nl0 + n;
            if (gn >= NW_) continue;
            const size_t rbase = (size_t)(mrow_base + gn) * (FD_ / 2) + 33 * c;
            const float r = __builtin_amdgcn_sqrtf(re[n] * re[n] + im[n] * im[n]);
            const float mag = flog1p(r);
            const float ph  = fatan2pi(im[n], re[n]);
            featP[rbase + tf] = (u32)f2bf(mag) | ((u32)f2bf(ph) << 16);
            if (tf == 0) {   // Nyquist bin -> cols 64/65 = dword 32
                const float a = flog1p(fabsf(rny[n]));
                const float p = (__float_as_uint(rny[n]) >> 31) ? 1.0f : 0.0f;
                featP[rbase + 32] = (u32)f2bf(a) | ((u32)f2bf(p) << 16);
            }
        }
    }
}

// ---------------------------------------------------------------------------
// gemm_mfma: C = tanh(A @ B^T + bias) * scale, bf16-split MFMA, fp32 accum.
// A: [M][Kd] as H (+L if HAS_AL) bf16 planes. B: [N][Kd] as H+L planes.
// Terms: Ah*Bh + Ah*Bl (+ Al*Bh). 128x128 tile, BK=32, 4 waves, 16x16x32.
// LDS XOR-swizzle (T2): pre-swizzled global k-chunk + swizzled ds_read.
// OUT_BF16: 1 -> write outH/outL bf16 planes, 0 -> write outF fp32.
// ---------------------------------------------------------------------------
template<bool HAS_AL, int OUT_BF16>
__global__ __launch_bounds__(256) void gemm_mfma_kernel(
        const u16* __restrict__ AH, const u16* __restrict__ AL,
        const u16* __restrict__ BH, const u16* __restrict__ BL,
        const float* __restrict__ bias, float scale,
        float* __restrict__ outF, u16* __restrict__ outH, u16* __restrict__ outL,
        int Mvalid, int N, int Kd) {
    const int bm = blockIdx.x, bn = blockIdx.y;
    const int tid = threadIdx.x;
    const int lane = tid & 63, w = tid >> 6;
    const int wr = w >> 1, wc = w & 1;
    const int m0 = bm * 128, n0 = bn * 128;

    __shared__ u16 smem[16384];   // 32 KB: AsH | AsL | BsH | BsL (8KB each)
    char* sA = (char*)smem;

    f32x4 acc[4][4];
#pragma unroll
    for (int i = 0; i < 4; ++i)
#pragma unroll
        for (int j = 0; j < 4; ++j) acc[i][j] = (f32x4){0.f, 0.f, 0.f, 0.f};

    const size_t rs = (size_t)Kd * 2;
    const char* gAH = (const char*)AH + (size_t)m0 * rs;
    const char* gAL = (const char*)AL + (size_t)m0 * rs;
    const char* gBH = (const char*)BH + (size_t)n0 * rs;
    const char* gBL = (const char*)BL + (size_t)n0 * rs;

    const int r0 = tid >> 2;
    // pre-swizzled global 16B-chunk offset (involution with read-side sl)
    const int kbs = (((tid & 3) ^ ((tid >> 2) & 3)) << 4);
    const int loff0 = tid * 16;
    const int sl = (((lane >> 4) ^ (lane & 3)) << 4);
    const int abase = (wr * 64 + (lane & 15)) * 64 + sl;
    const int bbase = (wc * 64 + (lane & 15)) * 64 + sl;

    for (int k0b = 0; k0b < Kd * 2; k0b += 64) {
#pragma unroll
        for (int i = 0; i < 2; ++i) {
            const size_t go = (size_t)(r0 + i * 64) * rs + (size_t)(k0b + kbs);
            const int lo = loff0 + i * 4096;
            gload16(gAH + go, sA + lo);
            if constexpr (HAS_AL) gload16(gAL + go, sA + 8192 + lo);
            gload16(gBH + go, sA + 16384 + lo);
            gload16(gBL + go, sA + 24576 + lo);
        }
        __syncthreads();

        bf16x8 ah[4], al[4], bh[4], bl[4];
#pragma unroll
        for (int f = 0; f < 4; ++f) {
            ah[f] = *(const bf16x8*)(sA + abase + f * 1024);
            if constexpr (HAS_AL) al[f] = *(const bf16x8*)(sA + 8192 + abase + f * 1024);
            bh[f] = *(const bf16x8*)(sA + 16384 + bbase + f * 1024);
            bl[f] = *(const bf16x8*)(sA + 24576 + bbase + f * 1024);
        }
#pragma unroll
        for (int fm = 0; fm < 4; ++fm)
#pragma unroll
            for (int fn = 0; fn < 4; ++fn) {
                acc[fm][fn] = __builtin_amdgcn_mfma_f32_16x16x32_bf16(ah[fm], bh[fn], acc[fm][fn], 0, 0, 0);
                acc[fm][fn] = __builtin_amdgcn_mfma_f32_16x16x32_bf16(ah[fm], bl[fn], acc[fm][fn], 0, 0, 0);
                if constexpr (HAS_AL)
                    acc[fm][fn] = __builtin_amdgcn_mfma_f32_16x16x32_bf16(al[fm], bh[fn], acc[fm][fn], 0, 0, 0);
            }
        __syncthreads();
    }

    float bv[4];
#pragma unroll
    for (int fn = 0; fn < 4; ++fn) bv[fn] = bias[n0 + wc * 64 + fn * 16 + (lane & 15)];
#pragma unroll
    for (int fm = 0; fm < 4; ++fm) {
        const int rbase = m0 + wr * 64 + fm * 16 + (lane >> 4) * 4;
#pragma unroll
        for (int fn = 0; fn < 4; ++fn) {
            const int col = n0 + wc * 64 + fn * 16 + (lane & 15);
#pragma unroll
            for (int r = 0; r < 4; ++r) {
                const int row = rbase + r;
                if (row < Mvalid) {
                    const float v = ftanh(acc[fm][fn][r] + bv[fn]) * scale;
                    if constexpr (OUT_BF16) {
                        const u16 h = f2bf(v);
                        outH[(size_t)row * N + col] = h;
                        outL[(size_t)row * N + col] = f2bf(v - bf2f(h));
                    } else {
                        outF[(size_t)row * N + col] = v;
                    }
                }
            }
        }
    }
}

// ---------------------------------------------------------------------------
// out_reduce: per b, out[b] = sum_n (h2[b,n,:]·Wout + bout) * wts[n]
// ---------------------------------------------------------------------------
__global__ __launch_bounds__(256) void out_reduce_kernel(const float* __restrict__ h2,
                                                         const float* __restrict__ Wout,
                                                         const float* __restrict__ bout,
                                                         const float* __restrict__ wts,
                                                         float* __restrict__ out) {
    const int bb = blockIdx.x;
    const int tid = threadIdx.x;
    __shared__ float wsh[HH_];
    __shared__ float red[256];
    if (tid < HH_) wsh[tid] = Wout[tid];
    __syncthreads();
    const float bo = bout[0];
    float acc = 0.f;
    for (int n = tid; n < NW_; n += 256) {
        const float* row = h2 + ((size_t)bb * NW_ + n) * HH_;
        float dot = 0.f;
#pragma unroll
        for (int j = 0; j < HH_; j += 4) {
            const float4 v = *(const float4*)(row + j);
            dot += v.x * wsh[j] + v.y * wsh[j + 1] + v.z * wsh[j + 2] + v.w * wsh[j + 3];
        }
        acc += (dot + bo) * wts[n];
    }
    red[tid] = acc;
    __syncthreads();
    for (int s = 128; s > 0; s >>= 1) {
        if (tid < s) red[tid] += red[tid + s];
        __syncthreads();
    }
    if (tid == 0) out[bb] = red[0];
}

// ---------------------------------------------------------------------------
extern "C" void kernel_launch(void* const* d_in, const int* in_sizes, int n_in,
                              void* d_out, int out_size, void* d_ws, size_t ws_size,
                              hipStream_t stream) {
    const float* x    = (const float*)d_in[0];
    const float* Wp   = (const float*)d_in[1];
    const float* bp   = (const float*)d_in[2];
    const float* W1   = (const float*)d_in[3];
    const float* b1   = (const float*)d_in[4];
    const float* W2   = (const float*)d_in[5];
    const float* b2   = (const float*)d_in[6];
    const float* Wout = (const float*)d_in[7];
    const float* bout = (const float*)d_in[8];
    const float* agg  = (const float*)d_in[9];
    float* out = (float*)d_out;

    char* wsb = (char*)d_ws;
    size_t off = 0;
    auto ra = [](size_t b) { return (b + 255) & ~(size_t)255; };
    auto alloc = [&](size_t bytes) -> char* {
        char* p = wsb + off;
        off += ra(bytes);
        return p;
    };

    u16* WpH = (u16*)alloc((size_t)MLP_ * FD_ * 2);
    u16* WpL = (u16*)alloc((size_t)MLP_ * FD_ * 2);
    u16* W1H = (u16*)alloc((size_t)HID_ * MLP_ * 2);
    u16* W1L = (u16*)alloc((size_t)HID_ * MLP_ * 2);
    u16* W2H = (u16*)alloc((size_t)HH_ * HID_ * 2);
    u16* W2L = (u16*)alloc((size_t)HH_ * HID_ * 2);
    float* wts = (float*)alloc((size_t)NW_ * 4);

    const size_t fixed = off;
    int NB = 32;
    for (;;) {
        const size_t M = (size_t)NB * NW_;
        const size_t Mp = ((M + 127) / 128) * 128;
        const size_t need = ra(Mp * FD_ * 2) +        // featH
                            4 * ra(Mp * 256 * 2) +    // projH/L, h1H/L
                            ra(Mp * 128 * 4);         // h2
        if (fixed + need <= ws_size || NB == 1) break;
        NB >>= 1;
    }
    const size_t Mmax  = (size_t)NB * NW_;
    const size_t MpMax = ((Mmax + 127) / 128) * 128;
    u16* featH = (u16*)alloc(MpMax * FD_ * 2);
    u16* projH = (u16*)alloc(MpMax * 256 * 2);
    u16* projL = (u16*)alloc(MpMax * 256 * 2);
    u16* h1H   = (u16*)alloc(MpMax * 256 * 2);
    u16* h1L   = (u16*)alloc(MpMax * 256 * 2);
    float* h2  = (float*)alloc(MpMax * 128 * 4);

    wconv_kernel<<<dim3(128), dim3(256), 0, stream>>>(Wp, WpH, WpL, MLP_ * FD_);
    wconv_kernel<<<dim3(32),  dim3(256), 0, stream>>>(W1, W1H, W1L, HID_ * MLP_);
    wconv_kernel<<<dim3(16),  dim3(256), 0, stream>>>(W2, W2H, W2L, HH_ * HID_);
    softmax_kernel<<<dim3(1), dim3(256), 0, stream>>>(agg, wts);

    for (int b0 = 0; b0 < B_; b0 += NB) {
        const int nb = (B_ - b0 < NB) ? (B_ - b0) : NB;
        const int M = nb * NW_;
        const int Mp = ((M + 127) / 128) * 128;

        feat_kernel<<<dim3(NT_, 4, nb), dim3(256), 0, stream>>>(
            x + (size_t)b0 * C_ * T_, (u32*)featH);

        gemm_mfma_kernel<false, 1><<<dim3(Mp / 128, 2), dim3(256), 0, stream>>>(
            featH, nullptr, WpH, WpL, bp, PI_F, nullptr, projH, projL, M, MLP_, FD_);

        gemm_mfma_kernel<true, 1><<<dim3(Mp / 128, 2), dim3(256), 0, stream>>>(
            projH, projL, W1H, W1L, b1, 1.0f, nullptr, h1H, h1L, M, HID_, MLP_);

        gemm_mfma_kernel<true, 0><<<dim3(Mp / 128, 1), dim3(256), 0, stream>>>(
            h1H, h1L, W2H, W2L, b2, 1.0f, h2, nullptr, nullptr, M, HH_, HID_);

        out_reduce_kernel<<<dim3(nb), dim3(256), 0, stream>>>(
            h2, Wout, bout, wts, out + b0);
    }
}

// Round 4
// 225.350 us; speedup vs baseline: 7.3579x; 2.1649x over previous
//
#include <hip/hip_runtime.h>
#include <math.h>

#define B_   32
#define C_   32
#define T_   1024
#define NF_  33
#define F2_  66      // NF*2
#define FD_  2112    // C_*F2_
#define NW_  961
#define MLP_ 256
#define HID_ 256
#define HH_  128
#define TN_  32
#define NT_  31      // ceil(961/32)

#define PI_F     3.14159265358979323846f
#define LN2_F    0.69314718055994530942f
#define L2E2_F   2.88539008177792681472f   // 2*log2(e)

typedef unsigned short u16;
typedef unsigned int   u32;
typedef __attribute__((ext_vector_type(8))) short bf16x8;
typedef __attribute__((ext_vector_type(4))) float f32x4;

__device__ __forceinline__ u16 f2bf(float f) {
    u32 u = __float_as_uint(f);
    u = u + 0x7FFFu + ((u >> 16) & 1u);   // RNE
    return (u16)(u >> 16);
}
__device__ __forceinline__ float bf2f(u16 h) {
    return __uint_as_float((u32)h << 16);
}
__device__ __forceinline__ void gload16(const void* g, void* l) {
    __builtin_amdgcn_global_load_lds(
        (const __attribute__((address_space(1))) void*)g,
        (__attribute__((address_space(3))) void*)l, 16, 0, 0);
}
__device__ __forceinline__ float ftanh(float x) {
    // tanh(x) = 1 - 2/(exp(2x)+1); exp2-based, inf-safe at both ends
    float z = __builtin_amdgcn_exp2f(x * L2E2_F);
    return 1.f - 2.f * __builtin_amdgcn_rcpf(z + 1.f);
}
__device__ __forceinline__ float flog1p(float x) {
    return __builtin_amdgcn_logf(1.f + x) * LN2_F;   // v_log_f32 is log2
}
// atan2(y,x)/pi, poly max err ~2e-6 (in pi units)
__device__ __forceinline__ float fatan2pi(float y, float x) {
    const float ay = fabsf(y), ax = fabsf(x);
    const float mn = fminf(ay, ax), mx = fmaxf(ay, ax);
    float t = mn * __builtin_amdgcn_rcpf(mx);
    t = (mx == 0.f) ? 0.f : t;
    const float s = t * t;
    float p = -0.00373098f;
    p = fmaf(p, s,  0.01676008f);
    p = fmaf(p, s, -0.03706162f);
    p = fmaf(p, s,  0.06160679f);
    p = fmaf(p, s, -0.10587735f);
    p = fmaf(p, s,  0.31830265f);
    p *= t;
    p = (ay > ax) ? 0.5f - p : p;
    p = (x < 0.f) ? 1.0f - p : p;
    return copysignf(p, y);
}

// ---------------------------------------------------------------------------
// wconv: fp32 weight matrix -> bf16 hi/lo planes (same layout)
// ---------------------------------------------------------------------------
__global__ __launch_bounds__(256) void wconv_kernel(const float* __restrict__ W,
                                                    u16* __restrict__ WH,
                                                    u16* __restrict__ WL,
                                                    int total) {
    for (int i = blockIdx.x * 256 + threadIdx.x; i < total; i += gridDim.x * 256) {
        const float v = W[i];
        const u16 h = f2bf(v);
        WH[i] = h;
        WL[i] = f2bf(v - bf2f(h));
    }
}

// ---------------------------------------------------------------------------
// softmax(agg) -> wts (single block)
// ---------------------------------------------------------------------------
__global__ __launch_bounds__(256) void softmax_kernel(const float* __restrict__ agg,
                                                      float* __restrict__ wts) {
    const int tid = threadIdx.x;
    __shared__ float red[256];
    float mx = -INFINITY;
    for (int i = tid; i < NW_; i += 256) mx = fmaxf(mx, agg[i]);
    red[tid] = mx; __syncthreads();
    for (int s = 128; s > 0; s >>= 1) {
        if (tid < s) red[tid] = fmaxf(red[tid], red[tid + s]);
        __syncthreads();
    }
    mx = red[0]; __syncthreads();
    float sm = 0.f;
    for (int i = tid; i < NW_; i += 256) sm += expf(agg[i] - mx);
    red[tid] = sm; __syncthreads();
    for (int s = 128; s > 0; s >>= 1) {
        if (tid < s) red[tid] += red[tid + s];
        __syncthreads();
    }
    const float inv = 1.f / red[0];
    for (int i = tid; i < NW_; i += 256) wts[i] = expf(agg[i] - mx) * inv;
}

// ---------------------------------------------------------------------------
// feat v3: SLIDING DFT. grid (31 tiles, 4 ch-groups, b). Block covers
// 8 channels x 32 windows x 33 bins. Phase 1: thread=(c8, bin f<32); one
// init DFT for window 0 (LDS basis, 2-way-free b64 reads), then 31 slides
// X' = (X - x_out + x_in) * e^{+2pi i f/64} (~6 ops/bin/window vs 256).
// Phase 2: Nyquist bin, thread=(c8, window j): alternating sum (no lane
// divergence). Packs (mag,ph) bf16 into one u32 store.
// ---------------------------------------------------------------------------
__global__ __launch_bounds__(256) void feat_kernel(const float* __restrict__ x,
                                                   u32* __restrict__ featP) {
    const int n0 = blockIdx.x * TN_;
    const int cg = blockIdx.y;
    const int bb = blockIdx.z;
    const int tid = threadIdx.x;
    const int tf = tid & 31;     // bin 0..31
    const int c8 = tid >> 5;     // channel-in-group 0..7
    const int c  = cg * 8 + c8;

    __shared__ float2 stab[64];          // e^{-i pi m/32} = (cos, -sin)
    __shared__ float xs[8][96];          // 3.0 KB
    __shared__ float basisT[64][68];     // 17.4 KB ([k][2f]=cos, [2f+1]=-sin)

    if (tid < 64) {
        float s, cc;
        sincosf(-PI_F * (float)tid / 32.0f, &s, &cc);
        stab[tid] = make_float2(cc, s);
    }
    __syncthreads();
    for (int e = tid; e < 2048; e += 256) {
        const int f = e >> 6, k = e & 63;
        const float2 w = stab[(f * k) & 63];
        basisT[k][2 * f]     = w.x;
        basisT[k][2 * f + 1] = w.y;
    }
    if (tid < 192) {
        const int cs = tid / 24, q = tid % 24;
        const int t0 = n0 + q * 4;
        const float* xb = x + ((size_t)bb * C_ + cg * 8 + cs) * T_;
        float4 v;
        if (t0 + 3 < T_) {
            v = *(const float4*)(xb + t0);
        } else {
            v.x = (t0 + 0 < T_) ? xb[t0 + 0] : 0.f;
            v.y = (t0 + 1 < T_) ? xb[t0 + 1] : 0.f;
            v.z = (t0 + 2 < T_) ? xb[t0 + 2] : 0.f;
            v.w = 0.f;
        }
        *(float4*)&xs[cs][q * 4] = v;
    }
    __syncthreads();

    const size_t rowb = (size_t)bb * NW_;

    // ---- phase 1: bins 0..31, sliding across 32 windows ----
    {
        float re = 0.f, im = 0.f;
#pragma unroll
        for (int k = 0; k < 64; ++k) {
            const float xv = xs[c8][k];
            const float2 w = *(const float2*)&basisT[k][2 * tf];
            re = fmaf(xv, w.x, re);
            im = fmaf(xv, w.y, im);
        }
        // slide twiddle: e^{+i pi tf/32} = conj(stab[tf])
        const float2 st = stab[tf];
        const float cx = st.x, sx = -st.y;

        for (int j = 0; j < TN_; ++j) {
            const int gn = n0 + j;
            if (gn >= NW_) break;    // uniform across block
            const float r   = __builtin_amdgcn_sqrtf(re * re + im * im);
            const float mag = flog1p(r);
            const float ph  = fatan2pi(im, re);
            featP[(rowb + gn) * (FD_ / 2) + 33 * c + tf] =
                (u32)f2bf(mag) | ((u32)f2bf(ph) << 16);
            // slide j -> j+1
            const float tre = re - xs[c8][j] + xs[c8][j + 64];
            re = tre * cx - im * sx;
            im = tre * sx + im * cx;
        }
    }

    // ---- phase 2: Nyquist bin (f=32), thread=(c8n, window j) ----
    {
        const int j   = tid & 31;
        const int c8n = tid >> 5;
        const int gn  = n0 + j;
        if (gn < NW_) {
            float s = 0.f;
#pragma unroll
            for (int k = 0; k < 32; ++k)
                s += xs[c8n][j + 2 * k] - xs[c8n][j + 2 * k + 1];
            const float a = flog1p(fabsf(s));
            const float p = (__float_as_uint(s) >> 31) ? 1.0f : 0.0f;
            featP[(rowb + gn) * (FD_ / 2) + 33 * (cg * 8 + c8n) + 32] =
                (u32)f2bf(a) | ((u32)f2bf(p) << 16);
        }
    }
}

// ---------------------------------------------------------------------------
// gemm_mfma: C = tanh(A @ B^T + bias) * scale, bf16-split MFMA, fp32 accum.
// A: [M][Kd] as H (+L if HAS_AL) bf16 planes. B: [N][Kd] as H+L planes.
// Terms: Ah*Bh + Ah*Bl (+ Al*Bh). 128x128 tile, BK=32, 4 waves, 16x16x32.
// LDS XOR-swizzle (T2): pre-swizzled global k-chunk + swizzled ds_read.
// OUT_BF16: 1 -> write outH/outL bf16 planes, 0 -> write outF fp32.
// ---------------------------------------------------------------------------
template<bool HAS_AL, int OUT_BF16>
__global__ __launch_bounds__(256) void gemm_mfma_kernel(
        const u16* __restrict__ AH, const u16* __restrict__ AL,
        const u16* __restrict__ BH, const u16* __restrict__ BL,
        const float* __restrict__ bias, float scale,
        float* __restrict__ outF, u16* __restrict__ outH, u16* __restrict__ outL,
        int Mvalid, int N, int Kd) {
    const int bm = blockIdx.x, bn = blockIdx.y;
    const int tid = threadIdx.x;
    const int lane = tid & 63, w = tid >> 6;
    const int wr = w >> 1, wc = w & 1;
    const int m0 = bm * 128, n0 = bn * 128;

    __shared__ u16 smem[16384];   // 32 KB: AsH | AsL | BsH | BsL (8KB each)
    char* sA = (char*)smem;

    f32x4 acc[4][4];
#pragma unroll
    for (int i = 0; i < 4; ++i)
#pragma unroll
        for (int j = 0; j < 4; ++j) acc[i][j] = (f32x4){0.f, 0.f, 0.f, 0.f};

    const size_t rs = (size_t)Kd * 2;
    const char* gAH = (const char*)AH + (size_t)m0 * rs;
    const char* gAL = (const char*)AL + (size_t)m0 * rs;
    const char* gBH = (const char*)BH + (size_t)n0 * rs;
    const char* gBL = (const char*)BL + (size_t)n0 * rs;

    const int r0 = tid >> 2;
    // pre-swizzled global 16B-chunk offset (involution with read-side sl)
    const int kbs = (((tid & 3) ^ ((tid >> 2) & 3)) << 4);
    const int loff0 = tid * 16;
    const int sl = (((lane >> 4) ^ (lane & 3)) << 4);
    const int abase = (wr * 64 + (lane & 15)) * 64 + sl;
    const int bbase = (wc * 64 + (lane & 15)) * 64 + sl;

    for (int k0b = 0; k0b < Kd * 2; k0b += 64) {
#pragma unroll
        for (int i = 0; i < 2; ++i) {
            const size_t go = (size_t)(r0 + i * 64) * rs + (size_t)(k0b + kbs);
            const int lo = loff0 + i * 4096;
            gload16(gAH + go, sA + lo);
            if constexpr (HAS_AL) gload16(gAL + go, sA + 8192 + lo);
            gload16(gBH + go, sA + 16384 + lo);
            gload16(gBL + go, sA + 24576 + lo);
        }
        __syncthreads();

        bf16x8 ah[4], al[4], bh[4], bl[4];
#pragma unroll
        for (int f = 0; f < 4; ++f) {
            ah[f] = *(const bf16x8*)(sA + abase + f * 1024);
            if constexpr (HAS_AL) al[f] = *(const bf16x8*)(sA + 8192 + abase + f * 1024);
            bh[f] = *(const bf16x8*)(sA + 16384 + bbase + f * 1024);
            bl[f] = *(const bf16x8*)(sA + 24576 + bbase + f * 1024);
        }
#pragma unroll
        for (int fm = 0; fm < 4; ++fm)
#pragma unroll
            for (int fn = 0; fn < 4; ++fn) {
                acc[fm][fn] = __builtin_amdgcn_mfma_f32_16x16x32_bf16(ah[fm], bh[fn], acc[fm][fn], 0, 0, 0);
                acc[fm][fn] = __builtin_amdgcn_mfma_f32_16x16x32_bf16(ah[fm], bl[fn], acc[fm][fn], 0, 0, 0);
                if constexpr (HAS_AL)
                    acc[fm][fn] = __builtin_amdgcn_mfma_f32_16x16x32_bf16(al[fm], bh[fn], acc[fm][fn], 0, 0, 0);
            }
        __syncthreads();
    }

    float bv[4];
#pragma unroll
    for (int fn = 0; fn < 4; ++fn) bv[fn] = bias[n0 + wc * 64 + fn * 16 + (lane & 15)];
#pragma unroll
    for (int fm = 0; fm < 4; ++fm) {
        const int rbase = m0 + wr * 64 + fm * 16 + (lane >> 4) * 4;
#pragma unroll
        for (int fn = 0; fn < 4; ++fn) {
            const int col = n0 + wc * 64 + fn * 16 + (lane & 15);
#pragma unroll
            for (int r = 0; r < 4; ++r) {
                const int row = rbase + r;
                if (row < Mvalid) {
                    const float v = ftanh(acc[fm][fn][r] + bv[fn]) * scale;
                    if constexpr (OUT_BF16) {
                        const u16 h = f2bf(v);
                        outH[(size_t)row * N + col] = h;
                        outL[(size_t)row * N + col] = f2bf(v - bf2f(h));
                    } else {
                        outF[(size_t)row * N + col] = v;
                    }
                }
            }
        }
    }
}

// ---------------------------------------------------------------------------
// out_reduce: per b, out[b] = sum_n (h2[b,n,:]·Wout + bout) * wts[n]
// ---------------------------------------------------------------------------
__global__ __launch_bounds__(256) void out_reduce_kernel(const float* __restrict__ h2,
                                                         const float* __restrict__ Wout,
                                                         const float* __restrict__ bout,
                                                         const float* __restrict__ wts,
                                                         float* __restrict__ out) {
    const int bb = blockIdx.x;
    const int tid = threadIdx.x;
    __shared__ float wsh[HH_];
    __shared__ float red[256];
    if (tid < HH_) wsh[tid] = Wout[tid];
    __syncthreads();
    const float bo = bout[0];
    float acc = 0.f;
    for (int n = tid; n < NW_; n += 256) {
        const float* row = h2 + ((size_t)bb * NW_ + n) * HH_;
        float dot = 0.f;
#pragma unroll
        for (int j = 0; j < HH_; j += 4) {
            const float4 v = *(const float4*)(row + j);
            dot += v.x * wsh[j] + v.y * wsh[j + 1] + v.z * wsh[j + 2] + v.w * wsh[j + 3];
        }
        acc += (dot + bo) * wts[n];
    }
    red[tid] = acc;
    __syncthreads();
    for (int s = 128; s > 0; s >>= 1) {
        if (tid < s) red[tid] += red[tid + s];
        __syncthreads();
    }
    if (tid == 0) out[bb] = red[0];
}

// ---------------------------------------------------------------------------
extern "C" void kernel_launch(void* const* d_in, const int* in_sizes, int n_in,
                              void* d_out, int out_size, void* d_ws, size_t ws_size,
                              hipStream_t stream) {
    const float* x    = (const float*)d_in[0];
    const float* Wp   = (const float*)d_in[1];
    const float* bp   = (const float*)d_in[2];
    const float* W1   = (const float*)d_in[3];
    const float* b1   = (const float*)d_in[4];
    const float* W2   = (const float*)d_in[5];
    const float* b2   = (const float*)d_in[6];
    const float* Wout = (const float*)d_in[7];
    const float* bout = (const float*)d_in[8];
    const float* agg  = (const float*)d_in[9];
    float* out = (float*)d_out;

    char* wsb = (char*)d_ws;
    size_t off = 0;
    auto ra = [](size_t b) { return (b + 255) & ~(size_t)255; };
    auto alloc = [&](size_t bytes) -> char* {
        char* p = wsb + off;
        off += ra(bytes);
        return p;
    };

    u16* WpH = (u16*)alloc((size_t)MLP_ * FD_ * 2);
    u16* WpL = (u16*)alloc((size_t)MLP_ * FD_ * 2);
    u16* W1H = (u16*)alloc((size_t)HID_ * MLP_ * 2);
    u16* W1L = (u16*)alloc((size_t)HID_ * MLP_ * 2);
    u16* W2H = (u16*)alloc((size_t)HH_ * HID_ * 2);
    u16* W2L = (u16*)alloc((size_t)HH_ * HID_ * 2);
    float* wts = (float*)alloc((size_t)NW_ * 4);

    const size_t fixed = off;
    int NB = 32;
    for (;;) {
        const size_t M = (size_t)NB * NW_;
        const size_t Mp = ((M + 127) / 128) * 128;
        const size_t need = ra(Mp * FD_ * 2) +        // featH
                            4 * ra(Mp * 256 * 2) +    // projH/L, h1H/L
                            ra(Mp * 128 * 4);         // h2
        if (fixed + need <= ws_size || NB == 1) break;
        NB >>= 1;
    }
    const size_t Mmax  = (size_t)NB * NW_;
    const size_t MpMax = ((Mmax + 127) / 128) * 128;
    u16* featH = (u16*)alloc(MpMax * FD_ * 2);
    u16* projH = (u16*)alloc(MpMax * 256 * 2);
    u16* projL = (u16*)alloc(MpMax * 256 * 2);
    u16* h1H   = (u16*)alloc(MpMax * 256 * 2);
    u16* h1L   = (u16*)alloc(MpMax * 256 * 2);
    float* h2  = (float*)alloc(MpMax * 128 * 4);

    wconv_kernel<<<dim3(128), dim3(256), 0, stream>>>(Wp, WpH, WpL, MLP_ * FD_);
    wconv_kernel<<<dim3(32),  dim3(256), 0, stream>>>(W1, W1H, W1L, HID_ * MLP_);
    wconv_kernel<<<dim3(16),  dim3(256), 0, stream>>>(W2, W2H, W2L, HH_ * HID_);
    softmax_kernel<<<dim3(1), dim3(256), 0, stream>>>(agg, wts);

    for (int b0 = 0; b0 < B_; b0 += NB) {
        const int nb = (B_ - b0 < NB) ? (B_ - b0) : NB;
        const int M = nb * NW_;
        const int Mp = ((M + 127) / 128) * 128;

        feat_kernel<<<dim3(NT_, 4, nb), dim3(256), 0, stream>>>(
            x + (size_t)b0 * C_ * T_, (u32*)featH);

        gemm_mfma_kernel<false, 1><<<dim3(Mp / 128, 2), dim3(256), 0, stream>>>(
            featH, nullptr, WpH, WpL, bp, PI_F, nullptr, projH, projL, M, MLP_, FD_);

        gemm_mfma_kernel<true, 1><<<dim3(Mp / 128, 2), dim3(256), 0, stream>>>(
            projH, projL, W1H, W1L, b1, 1.0f, nullptr, h1H, h1L, M, HID_, MLP_);

        gemm_mfma_kernel<true, 0><<<dim3(Mp / 128, 1), dim3(256), 0, stream>>>(
            h1H, h1L, W2H, W2L, b2, 1.0f, h2, nullptr, nullptr, M, HH_, HID_);

        out_reduce_kernel<<<dim3(nb), dim3(256), 0, stream>>>(
            h2, Wout, bout, wts, out + b0);
    }
}

// Round 5
// 215.105 us; speedup vs baseline: 7.7084x; 1.0476x over previous
//
#include <hip/hip_runtime.h>
#include <math.h>

#define B_   32
#define C_   32
#define T_   1024
#define NF_  33
#define F2_  66      // NF*2
#define FD_  2112    // C_*F2_
#define NW_  961
#define MLP_ 256
#define HID_ 256
#define HH_  128
#define TN_  32
#define NT_  31      // ceil(961/32)

#define PI_F     3.14159265358979323846f
#define LN2_F    0.69314718055994530942f
#define L2E2_F   2.88539008177792681472f   // 2*log2(e)

typedef unsigned short u16;
typedef unsigned int   u32;
typedef __attribute__((ext_vector_type(8))) short bf16x8;
typedef __attribute__((ext_vector_type(4))) float f32x4;

__device__ __forceinline__ u16 f2bf(float f) {
    u32 u = __float_as_uint(f);
    u = u + 0x7FFFu + ((u >> 16) & 1u);   // RNE
    return (u16)(u >> 16);
}
__device__ __forceinline__ float bf2f(u16 h) {
    return __uint_as_float((u32)h << 16);
}
__device__ __forceinline__ void gload16(const void* g, void* l) {
    __builtin_amdgcn_global_load_lds(
        (const __attribute__((address_space(1))) void*)g,
        (__attribute__((address_space(3))) void*)l, 16, 0, 0);
}
__device__ __forceinline__ float ftanh(float x) {
    float z = __builtin_amdgcn_exp2f(x * L2E2_F);
    return 1.f - 2.f * __builtin_amdgcn_rcpf(z + 1.f);
}
__device__ __forceinline__ float flog1p(float x) {
    return __builtin_amdgcn_logf(1.f + x) * LN2_F;   // v_log_f32 is log2
}
// atan2(y,x)/pi, poly max err ~2e-6 (in pi units)
__device__ __forceinline__ float fatan2pi(float y, float x) {
    const float ay = fabsf(y), ax = fabsf(x);
    const float mn = fminf(ay, ax), mx = fmaxf(ay, ax);
    float t = mn * __builtin_amdgcn_rcpf(mx);
    t = (mx == 0.f) ? 0.f : t;
    const float s = t * t;
    float p = -0.00373098f;
    p = fmaf(p, s,  0.01676008f);
    p = fmaf(p, s, -0.03706162f);
    p = fmaf(p, s,  0.06160679f);
    p = fmaf(p, s, -0.10587735f);
    p = fmaf(p, s,  0.31830265f);
    p *= t;
    p = (ay > ax) ? 0.5f - p : p;
    p = (x < 0.f) ? 1.0f - p : p;
    return copysignf(p, y);
}

// ---------------------------------------------------------------------------
// wconv: fp32 weight matrix -> bf16 hi/lo planes (same layout)
// ---------------------------------------------------------------------------
__global__ __launch_bounds__(256) void wconv_kernel(const float* __restrict__ W,
                                                    u16* __restrict__ WH,
                                                    u16* __restrict__ WL,
                                                    int total) {
    for (int i = blockIdx.x * 256 + threadIdx.x; i < total; i += gridDim.x * 256) {
        const float v = W[i];
        const u16 h = f2bf(v);
        WH[i] = h;
        WL[i] = f2bf(v - bf2f(h));
    }
}

// ---------------------------------------------------------------------------
// softmax(agg) -> wts (single block)
// ---------------------------------------------------------------------------
__global__ __launch_bounds__(256) void softmax_kernel(const float* __restrict__ agg,
                                                      float* __restrict__ wts) {
    const int tid = threadIdx.x;
    __shared__ float red[256];
    float mx = -INFINITY;
    for (int i = tid; i < NW_; i += 256) mx = fmaxf(mx, agg[i]);
    red[tid] = mx; __syncthreads();
    for (int s = 128; s > 0; s >>= 1) {
        if (tid < s) red[tid] = fmaxf(red[tid], red[tid + s]);
        __syncthreads();
    }
    mx = red[0]; __syncthreads();
    float sm = 0.f;
    for (int i = tid; i < NW_; i += 256) sm += expf(agg[i] - mx);
    red[tid] = sm; __syncthreads();
    for (int s = 128; s > 0; s >>= 1) {
        if (tid < s) red[tid] += red[tid + s];
        __syncthreads();
    }
    const float inv = 1.f / red[0];
    for (int i = tid; i < NW_; i += 256) wts[i] = expf(agg[i] - mx) * inv;
}

// ---------------------------------------------------------------------------
// feat v3: SLIDING DFT (unchanged from round 4).
// ---------------------------------------------------------------------------
__global__ __launch_bounds__(256) void feat_kernel(const float* __restrict__ x,
                                                   u32* __restrict__ featP) {
    const int n0 = blockIdx.x * TN_;
    const int cg = blockIdx.y;
    const int bb = blockIdx.z;
    const int tid = threadIdx.x;
    const int tf = tid & 31;     // bin 0..31
    const int c8 = tid >> 5;     // channel-in-group 0..7
    const int c  = cg * 8 + c8;

    __shared__ float2 stab[64];
    __shared__ float xs[8][96];
    __shared__ float basisT[64][68];

    if (tid < 64) {
        float s, cc;
        sincosf(-PI_F * (float)tid / 32.0f, &s, &cc);
        stab[tid] = make_float2(cc, s);
    }
    __syncthreads();
    for (int e = tid; e < 2048; e += 256) {
        const int f = e >> 6, k = e & 63;
        const float2 w = stab[(f * k) & 63];
        basisT[k][2 * f]     = w.x;
        basisT[k][2 * f + 1] = w.y;
    }
    if (tid < 192) {
        const int cs = tid / 24, q = tid % 24;
        const int t0 = n0 + q * 4;
        const float* xb = x + ((size_t)bb * C_ + cg * 8 + cs) * T_;
        float4 v;
        if (t0 + 3 < T_) {
            v = *(const float4*)(xb + t0);
        } else {
            v.x = (t0 + 0 < T_) ? xb[t0 + 0] : 0.f;
            v.y = (t0 + 1 < T_) ? xb[t0 + 1] : 0.f;
            v.z = (t0 + 2 < T_) ? xb[t0 + 2] : 0.f;
            v.w = 0.f;
        }
        *(float4*)&xs[cs][q * 4] = v;
    }
    __syncthreads();

    const size_t rowb = (size_t)bb * NW_;

    // ---- phase 1: bins 0..31, sliding across 32 windows ----
    {
        float re = 0.f, im = 0.f;
#pragma unroll
        for (int k = 0; k < 64; ++k) {
            const float xv = xs[c8][k];
            const float2 w = *(const float2*)&basisT[k][2 * tf];
            re = fmaf(xv, w.x, re);
            im = fmaf(xv, w.y, im);
        }
        const float2 st = stab[tf];
        const float cx = st.x, sx = -st.y;

        for (int j = 0; j < TN_; ++j) {
            const int gn = n0 + j;
            if (gn >= NW_) break;
            const float r   = __builtin_amdgcn_sqrtf(re * re + im * im);
            const float mag = flog1p(r);
            const float ph  = fatan2pi(im, re);
            featP[(rowb + gn) * (FD_ / 2) + 33 * c + tf] =
                (u32)f2bf(mag) | ((u32)f2bf(ph) << 16);
            const float tre = re - xs[c8][j] + xs[c8][j + 64];
            re = tre * cx - im * sx;
            im = tre * sx + im * cx;
        }
    }

    // ---- phase 2: Nyquist bin ----
    {
        const int j   = tid & 31;
        const int c8n = tid >> 5;
        const int gn  = n0 + j;
        if (gn < NW_) {
            float s = 0.f;
#pragma unroll
            for (int k = 0; k < 32; ++k)
                s += xs[c8n][j + 2 * k] - xs[c8n][j + 2 * k + 1];
            const float a = flog1p(fabsf(s));
            const float p = (__float_as_uint(s) >> 31) ? 1.0f : 0.0f;
            featP[(rowb + gn) * (FD_ / 2) + 33 * (cg * 8 + c8n) + 32] =
                (u32)f2bf(a) | ((u32)f2bf(p) << 16);
        }
    }
}

// ---------------------------------------------------------------------------
// gemm2ph: 2-phase double-buffered MFMA GEMM, BM=128 x BN=256 (full N),
// BK=32, 512 threads / 8 waves (2x4 of 64x64). STAGE(next) issued BEFORE
// compute(cur); single __syncthreads per K-step drains prefetch AFTER the
// MFMA work, hiding HBM latency (guide T3 minimum-2-phase recipe).
// C = tanh(A @ B^T + bias) * scale. A: H (+L) planes; B: H+L planes.
// ---------------------------------------------------------------------------
template<bool HAS_AL>
__global__ __launch_bounds__(512, 2) void gemm2ph_kernel(
        const u16* __restrict__ AH, const u16* __restrict__ AL,
        const u16* __restrict__ BH, const u16* __restrict__ BL,
        const float* __restrict__ bias, float scale,
        u16* __restrict__ outH, u16* __restrict__ outL,
        int Mvalid, int Kd) {
    const int bm = blockIdx.x;
    const int tid = threadIdx.x;
    const int lane = tid & 63, w = tid >> 6;
    const int wr = w >> 2, wc = w & 3;           // 2 x 4 waves of 64x64
    const int m0 = bm * 128;

    // LDS layout (bytes):
    //  A H: buf0 @0, buf1 @8192   (8KB each)
    //  A L: buf0 @16384, buf1 @24576 (if HAS_AL)
    //  B H: offB + buf*16384      (16KB each)
    //  B L: offB + 32768 + buf*16384
    constexpr int offB = HAS_AL ? 32768 : 16384;
    __shared__ char sA[offB + 65536];

    f32x4 acc[4][4];
#pragma unroll
    for (int i = 0; i < 4; ++i)
#pragma unroll
        for (int j = 0; j < 4; ++j) acc[i][j] = (f32x4){0.f, 0.f, 0.f, 0.f};

    const size_t rs = (size_t)Kd * 2;
    const char* gAH = (const char*)AH + (size_t)m0 * rs;
    const char* gAL = (const char*)AL + (size_t)m0 * rs;
    const char* gBH = (const char*)BH;
    const char* gBL = (const char*)BL;

    // staging indices: A 1 chunk/thread, B 2 chunks/thread/plane
    const int arow = tid >> 2, akc = tid & 3;
    const size_t aswz = (size_t)((akc ^ (arow & 3)) << 4);
    const int brow0 = tid >> 2, bkc0 = tid & 3;
    const int brow1 = (tid + 512) >> 2, bkc1 = tid & 3;   // +512 keeps kc
    const size_t bswz0 = (size_t)((bkc0 ^ (brow0 & 3)) << 4);
    const size_t bswz1 = (size_t)((bkc1 ^ (brow1 & 3)) << 4);

    // read-side fragment addressing (row stride 64B, XOR involution)
    const int sl = (((lane >> 4) ^ (lane & 3)) << 4);
    const int abase = (wr * 64 + (lane & 15)) * 64 + sl;
    const int bbase = (wc * 64 + (lane & 15)) * 64 + sl;

    const int nt = Kd >> 5;   // K-steps of 32

    auto stage = [&](int buf, int t) {
        const size_t k0b = (size_t)t * 64;
        gload16(gAH + (size_t)arow * rs + k0b + aswz,
                sA + buf * 8192 + tid * 16);
        if constexpr (HAS_AL)
            gload16(gAL + (size_t)arow * rs + k0b + aswz,
                    sA + 16384 + buf * 8192 + tid * 16);
        gload16(gBH + (size_t)brow0 * rs + k0b + bswz0,
                sA + offB + buf * 16384 + tid * 16);
        gload16(gBH + (size_t)brow1 * rs + k0b + bswz1,
                sA + offB + buf * 16384 + (tid + 512) * 16);
        gload16(gBL + (size_t)brow0 * rs + k0b + bswz0,
                sA + offB + 32768 + buf * 16384 + tid * 16);
        gload16(gBL + (size_t)brow1 * rs + k0b + bswz1,
                sA + offB + 32768 + buf * 16384 + (tid + 512) * 16);
    };

    stage(0, 0);
    __syncthreads();

    int cur = 0;
    for (int t = 0; t < nt; ++t) {
        if (t + 1 < nt) stage(cur ^ 1, t + 1);

        const char* aBuf  = sA + cur * 8192;
        const char* alBuf = sA + 16384 + cur * 8192;
        const char* bhBuf = sA + offB + cur * 16384;
        const char* blBuf = sA + offB + 32768 + cur * 16384;

        bf16x8 ah[4], al[4], bh[4], bl[4];
#pragma unroll
        for (int f = 0; f < 4; ++f) {
            ah[f] = *(const bf16x8*)(aBuf + abase + f * 1024);
            if constexpr (HAS_AL) al[f] = *(const bf16x8*)(alBuf + abase + f * 1024);
            bh[f] = *(const bf16x8*)(bhBuf + bbase + f * 1024);
            bl[f] = *(const bf16x8*)(blBuf + bbase + f * 1024);
        }
#pragma unroll
        for (int fm = 0; fm < 4; ++fm)
#pragma unroll
            for (int fn = 0; fn < 4; ++fn) {
                acc[fm][fn] = __builtin_amdgcn_mfma_f32_16x16x32_bf16(ah[fm], bh[fn], acc[fm][fn], 0, 0, 0);
                acc[fm][fn] = __builtin_amdgcn_mfma_f32_16x16x32_bf16(ah[fm], bl[fn], acc[fm][fn], 0, 0, 0);
                if constexpr (HAS_AL)
                    acc[fm][fn] = __builtin_amdgcn_mfma_f32_16x16x32_bf16(al[fm], bh[fn], acc[fm][fn], 0, 0, 0);
            }
        __syncthreads();   // drains the prefetch issued above (after compute)
        cur ^= 1;
    }

    float bv[4];
#pragma unroll
    for (int fn = 0; fn < 4; ++fn) bv[fn] = bias[wc * 64 + fn * 16 + (lane & 15)];
#pragma unroll
    for (int fm = 0; fm < 4; ++fm) {
        const int rbase = m0 + wr * 64 + fm * 16 + (lane >> 4) * 4;
#pragma unroll
        for (int fn = 0; fn < 4; ++fn) {
            const int col = wc * 64 + fn * 16 + (lane & 15);
#pragma unroll
            for (int r = 0; r < 4; ++r) {
                const int row = rbase + r;
                if (row < Mvalid) {
                    const float v = ftanh(acc[fm][fn][r] + bv[fn]) * scale;
                    const u16 h = f2bf(v);
                    outH[(size_t)row * 256 + col] = h;
                    outL[(size_t)row * 256 + col] = f2bf(v - bf2f(h));
                }
            }
        }
    }
}

// ---------------------------------------------------------------------------
// gemm_mfma: (round-4 kernel, kept for the final 128-wide layer)
// ---------------------------------------------------------------------------
template<bool HAS_AL, int OUT_BF16>
__global__ __launch_bounds__(256) void gemm_mfma_kernel(
        const u16* __restrict__ AH, const u16* __restrict__ AL,
        const u16* __restrict__ BH, const u16* __restrict__ BL,
        const float* __restrict__ bias, float scale,
        float* __restrict__ outF, u16* __restrict__ outH, u16* __restrict__ outL,
        int Mvalid, int N, int Kd) {
    const int bm = blockIdx.x, bn = blockIdx.y;
    const int tid = threadIdx.x;
    const int lane = tid & 63, w = tid >> 6;
    const int wr = w >> 1, wc = w & 1;
    const int m0 = bm * 128, n0 = bn * 128;

    __shared__ u16 smem[16384];
    char* sA = (char*)smem;

    f32x4 acc[4][4];
#pragma unroll
    for (int i = 0; i < 4; ++i)
#pragma unroll
        for (int j = 0; j < 4; ++j) acc[i][j] = (f32x4){0.f, 0.f, 0.f, 0.f};

    const size_t rs = (size_t)Kd * 2;
    const char* gAH = (const char*)AH + (size_t)m0 * rs;
    const char* gAL = (const char*)AL + (size_t)m0 * rs;
    const char* gBH = (const char*)BH + (size_t)n0 * rs;
    const char* gBL = (const char*)BL + (size_t)n0 * rs;

    const int r0 = tid >> 2;
    const int kbs = (((tid & 3) ^ ((tid >> 2) & 3)) << 4);
    const int loff0 = tid * 16;
    const int sl = (((lane >> 4) ^ (lane & 3)) << 4);
    const int abase = (wr * 64 + (lane & 15)) * 64 + sl;
    const int bbase = (wc * 64 + (lane & 15)) * 64 + sl;

    for (int k0b = 0; k0b < Kd * 2; k0b += 64) {
#pragma unroll
        for (int i = 0; i < 2; ++i) {
            const size_t go = (size_t)(r0 + i * 64) * rs + (size_t)(k0b + kbs);
            const int lo = loff0 + i * 4096;
            gload16(gAH + go, sA + lo);
            if constexpr (HAS_AL) gload16(gAL + go, sA + 8192 + lo);
            gload16(gBH + go, sA + 16384 + lo);
            gload16(gBL + go, sA + 24576 + lo);
        }
        __syncthreads();

        bf16x8 ah[4], al[4], bh[4], bl[4];
#pragma unroll
        for (int f = 0; f < 4; ++f) {
            ah[f] = *(const bf16x8*)(sA + abase + f * 1024);
            if constexpr (HAS_AL) al[f] = *(const bf16x8*)(sA + 8192 + abase + f * 1024);
            bh[f] = *(const bf16x8*)(sA + 16384 + bbase + f * 1024);
            bl[f] = *(const bf16x8*)(sA + 24576 + bbase + f * 1024);
        }
#pragma unroll
        for (int fm = 0; fm < 4; ++fm)
#pragma unroll
            for (int fn = 0; fn < 4; ++fn) {
                acc[fm][fn] = __builtin_amdgcn_mfma_f32_16x16x32_bf16(ah[fm], bh[fn], acc[fm][fn], 0, 0, 0);
                acc[fm][fn] = __builtin_amdgcn_mfma_f32_16x16x32_bf16(ah[fm], bl[fn], acc[fm][fn], 0, 0, 0);
                if constexpr (HAS_AL)
                    acc[fm][fn] = __builtin_amdgcn_mfma_f32_16x16x32_bf16(al[fm], bh[fn], acc[fm][fn], 0, 0, 0);
            }
        __syncthreads();
    }

    float bv[4];
#pragma unroll
    for (int fn = 0; fn < 4; ++fn) bv[fn] = bias[n0 + wc * 64 + fn * 16 + (lane & 15)];
#pragma unroll
    for (int fm = 0; fm < 4; ++fm) {
        const int rbase = m0 + wr * 64 + fm * 16 + (lane >> 4) * 4;
#pragma unroll
        for (int fn = 0; fn < 4; ++fn) {
            const int col = n0 + wc * 64 + fn * 16 + (lane & 15);
#pragma unroll
            for (int r = 0; r < 4; ++r) {
                const int row = rbase + r;
                if (row < Mvalid) {
                    const float v = ftanh(acc[fm][fn][r] + bv[fn]) * scale;
                    if constexpr (OUT_BF16) {
                        const u16 h = f2bf(v);
                        outH[(size_t)row * N + col] = h;
                        outL[(size_t)row * N + col] = f2bf(v - bf2f(h));
                    } else {
                        outF[(size_t)row * N + col] = v;
                    }
                }
            }
        }
    }
}

// ---------------------------------------------------------------------------
// out_reduce: per b, out[b] = sum_n (h2[b,n,:]·Wout + bout) * wts[n]
// ---------------------------------------------------------------------------
__global__ __launch_bounds__(256) void out_reduce_kernel(const float* __restrict__ h2,
                                                         const float* __restrict__ Wout,
                                                         const float* __restrict__ bout,
                                                         const float* __restrict__ wts,
                                                         float* __restrict__ out) {
    const int bb = blockIdx.x;
    const int tid = threadIdx.x;
    __shared__ float wsh[HH_];
    __shared__ float red[256];
    if (tid < HH_) wsh[tid] = Wout[tid];
    __syncthreads();
    const float bo = bout[0];
    float acc = 0.f;
    for (int n = tid; n < NW_; n += 256) {
        const float* row = h2 + ((size_t)bb * NW_ + n) * HH_;
        float dot = 0.f;
#pragma unroll
        for (int j = 0; j < HH_; j += 4) {
            const float4 v = *(const float4*)(row + j);
            dot += v.x * wsh[j] + v.y * wsh[j + 1] + v.z * wsh[j + 2] + v.w * wsh[j + 3];
        }
        acc += (dot + bo) * wts[n];
    }
    red[tid] = acc;
    __syncthreads();
    for (int s = 128; s > 0; s >>= 1) {
        if (tid < s) red[tid] += red[tid + s];
        __syncthreads();
    }
    if (tid == 0) out[bb] = red[0];
}

// ---------------------------------------------------------------------------
extern "C" void kernel_launch(void* const* d_in, const int* in_sizes, int n_in,
                              void* d_out, int out_size, void* d_ws, size_t ws_size,
                              hipStream_t stream) {
    const float* x    = (const float*)d_in[0];
    const float* Wp   = (const float*)d_in[1];
    const float* bp   = (const float*)d_in[2];
    const float* W1   = (const float*)d_in[3];
    const float* b1   = (const float*)d_in[4];
    const float* W2   = (const float*)d_in[5];
    const float* b2   = (const float*)d_in[6];
    const float* Wout = (const float*)d_in[7];
    const float* bout = (const float*)d_in[8];
    const float* agg  = (const float*)d_in[9];
    float* out = (float*)d_out;

    char* wsb = (char*)d_ws;
    size_t off = 0;
    auto ra = [](size_t b) { return (b + 255) & ~(size_t)255; };
    auto alloc = [&](size_t bytes) -> char* {
        char* p = wsb + off;
        off += ra(bytes);
        return p;
    };

    u16* WpH = (u16*)alloc((size_t)MLP_ * FD_ * 2);
    u16* WpL = (u16*)alloc((size_t)MLP_ * FD_ * 2);
    u16* W1H = (u16*)alloc((size_t)HID_ * MLP_ * 2);
    u16* W1L = (u16*)alloc((size_t)HID_ * MLP_ * 2);
    u16* W2H = (u16*)alloc((size_t)HH_ * HID_ * 2);
    u16* W2L = (u16*)alloc((size_t)HH_ * HID_ * 2);
    float* wts = (float*)alloc((size_t)NW_ * 4);

    const size_t fixed = off;
    int NB = 32;
    for (;;) {
        const size_t M = (size_t)NB * NW_;
        const size_t Mp = ((M + 127) / 128) * 128;
        const size_t need = ra(Mp * FD_ * 2) +        // featH
                            4 * ra(Mp * 256 * 2) +    // projH/L, h1H/L
                            ra(Mp * 128 * 4);         // h2
        if (fixed + need <= ws_size || NB == 1) break;
        NB >>= 1;
    }
    const size_t Mmax  = (size_t)NB * NW_;
    const size_t MpMax = ((Mmax + 127) / 128) * 128;
    u16* featH = (u16*)alloc(MpMax * FD_ * 2);
    u16* projH = (u16*)alloc(MpMax * 256 * 2);
    u16* projL = (u16*)alloc(MpMax * 256 * 2);
    u16* h1H   = (u16*)alloc(MpMax * 256 * 2);
    u16* h1L   = (u16*)alloc(MpMax * 256 * 2);
    float* h2  = (float*)alloc(MpMax * 128 * 4);

    wconv_kernel<<<dim3(128), dim3(256), 0, stream>>>(Wp, WpH, WpL, MLP_ * FD_);
    wconv_kernel<<<dim3(32),  dim3(256), 0, stream>>>(W1, W1H, W1L, HID_ * MLP_);
    wconv_kernel<<<dim3(16),  dim3(256), 0, stream>>>(W2, W2H, W2L, HH_ * HID_);
    softmax_kernel<<<dim3(1), dim3(256), 0, stream>>>(agg, wts);

    for (int b0 = 0; b0 < B_; b0 += NB) {
        const int nb = (B_ - b0 < NB) ? (B_ - b0) : NB;
        const int M = nb * NW_;
        const int Mp = ((M + 127) / 128) * 128;

        feat_kernel<<<dim3(NT_, 4, nb), dim3(256), 0, stream>>>(
            x + (size_t)b0 * C_ * T_, (u32*)featH);

        // proj: N=256 full-width, 2-phase dbuf, A read once
        gemm2ph_kernel<false><<<dim3(Mp / 128), dim3(512), 0, stream>>>(
            featH, nullptr, WpH, WpL, bp, PI_F, projH, projL, M, FD_);

        // h1: N=256 full-width, 3-term
        gemm2ph_kernel<true><<<dim3(Mp / 128), dim3(512), 0, stream>>>(
            projH, projL, W1H, W1L, b1, 1.0f, h1H, h1L, M, MLP_);

        // h2: N=128 (round-4 kernel)
        gemm_mfma_kernel<true, 0><<<dim3(Mp / 128, 1), dim3(256), 0, stream>>>(
            h1H, h1L, W2H, W2L, b2, 1.0f, h2, nullptr, nullptr, M, HH_, HID_);

        out_reduce_kernel<<<dim3(nb), dim3(256), 0, stream>>>(
            h2, Wout, bout, wts, out + b0);
    }
}